// Round 1
// baseline (593.003 us; speedup 1.0000x reference)
//
#include <hip/hip_runtime.h>
#include <hip/hip_bf16.h>

#define B_   64
#define L_   512
#define H_   256
#define H2_  512
#define HALF_ 128
#define V_   32000
#define NTOK_ (B_*L_)

__device__ __forceinline__ float wave_reduce_sum(float v) {
#pragma unroll
    for (int off = 32; off > 0; off >>= 1) v += __shfl_xor(v, off, 64);
    return v;
}

// ---------------------------------------------------------------------------
// K1: fused embed-gather + FFN (relu(e@W1+b1)@W2+b2) + residual + LayerNorm
// 32 tokens per 256-thread block. Thread (wave wv, lane) owns 8 tokens x 4 cols
// (cols = lane, lane+64, lane+128, lane+192). e and ff1 staged row-major in LDS;
// inner-loop LDS reads are wave-uniform (broadcast, conflict-free).
// ---------------------------------------------------------------------------
__global__ __launch_bounds__(256) void k_encode(
    const int* __restrict__ seq, const float* __restrict__ embed,
    const float* __restrict__ W1, const float* __restrict__ b1,
    const float* __restrict__ W2, const float* __restrict__ b2,
    const float* __restrict__ ln_g, const float* __restrict__ ln_b,
    float* __restrict__ hout)
{
    __shared__ float e_s[32][H_];   // 32 KB
    __shared__ float f_s[32][H_];   // 32 KB (ff1 half, reused across halves)
    const int t    = threadIdx.x;
    const int lane = t & 63;
    const int wv   = t >> 6;                 // wave id = token subgroup
    const int tokBase = blockIdx.x * 32;

    // gather: 8 threads per token, 8 float4 each
    {
        const int tk = t >> 3;
        const int part = t & 7;
        const long row = (long)seq[tokBase + tk] * H_;
        const float4* src = reinterpret_cast<const float4*>(embed + row);
        float4* dst = reinterpret_cast<float4*>(&e_s[tk][0]);
#pragma unroll
        for (int i = 0; i < 8; ++i) dst[part + 8*i] = src[part + 8*i];
    }
    __syncthreads();

    float acc2[8][4];
#pragma unroll
    for (int i = 0; i < 8; ++i)
#pragma unroll
        for (int j = 0; j < 4; ++j) acc2[i][j] = 0.f;

    for (int half = 0; half < 2; ++half) {
        // ---- ff1 = relu(e @ W1[:, half*256 + c] + b1) ----
        float a1[8][4];
        {
            float bv[4];
#pragma unroll
            for (int j = 0; j < 4; ++j) bv[j] = b1[half*256 + lane + 64*j];
#pragma unroll
            for (int i = 0; i < 8; ++i)
#pragma unroll
                for (int j = 0; j < 4; ++j) a1[i][j] = bv[j];
        }
#pragma unroll 4
        for (int k = 0; k < H_; ++k) {
            float w[4];
#pragma unroll
            for (int j = 0; j < 4; ++j) w[j] = W1[k*H2_ + half*256 + lane + 64*j];
#pragma unroll
            for (int i = 0; i < 8; ++i) {
                float ev = e_s[wv*8 + i][k];          // wave-uniform broadcast
#pragma unroll
                for (int j = 0; j < 4; ++j) a1[i][j] = fmaf(ev, w[j], a1[i][j]);
            }
        }
        if (half) __syncthreads();   // previous-half readers of f_s must finish
#pragma unroll
        for (int i = 0; i < 8; ++i)
#pragma unroll
            for (int j = 0; j < 4; ++j)
                f_s[wv*8 + i][lane + 64*j] = fmaxf(a1[i][j], 0.f);
        __syncthreads();
        // ---- acc2 += ff1 @ W2[half*256 + k2, :] ----
#pragma unroll 4
        for (int k2 = 0; k2 < H_; ++k2) {
            float w[4];
#pragma unroll
            for (int j = 0; j < 4; ++j) w[j] = W2[(half*256 + k2)*H_ + lane + 64*j];
#pragma unroll
            for (int i = 0; i < 8; ++i) {
                float fv = f_s[wv*8 + i][k2];         // wave-uniform broadcast
#pragma unroll
                for (int j = 0; j < 4; ++j) acc2[i][j] = fmaf(fv, w[j], acc2[i][j]);
            }
        }
    }

    // ---- x = e + ff2 + b2; LayerNorm over H; write h ----
    {
        float bv[4];
#pragma unroll
        for (int j = 0; j < 4; ++j) bv[j] = b2[lane + 64*j];
        float mu[8], rstd[8];
#pragma unroll
        for (int i = 0; i < 8; ++i) {
            float s = 0.f, s2 = 0.f;
#pragma unroll
            for (int j = 0; j < 4; ++j) {
                float xv = e_s[wv*8 + i][lane + 64*j] + acc2[i][j] + bv[j];
                acc2[i][j] = xv;                     // reuse acc2 as x
                s += xv; s2 = fmaf(xv, xv, s2);
            }
            s  = wave_reduce_sum(s);
            s2 = wave_reduce_sum(s2);
            mu[i] = s * (1.f/256.f);
            float var = s2 * (1.f/256.f) - mu[i]*mu[i];
            rstd[i] = rsqrtf(var + 1e-5f);
        }
#pragma unroll
        for (int j = 0; j < 4; ++j) {
            int col = lane + 64*j;
            float g = ln_g[col], bb = ln_b[col];
#pragma unroll
            for (int i = 0; i < 8; ++i)
                hout[(long)(tokBase + wv*8 + i)*H_ + col] =
                    (acc2[i][j] - mu[i]) * rstd[i] * g + bb;
        }
    }
}

// ---------------------------------------------------------------------------
// K2: ks = h@Wsem+bsem, ke = h@Wepi+bepi for ALL tokens (token 511 doubles as q),
// plus beta = 1/(||k||^2 + 1e-6) per token/matrix.
// ---------------------------------------------------------------------------
__global__ __launch_bounds__(256) void k_proj(
    const float* __restrict__ hin,
    const float* __restrict__ Wsem, const float* __restrict__ bsem,
    const float* __restrict__ Wepi, const float* __restrict__ bepi,
    float* __restrict__ ks, float* __restrict__ ke,
    float* __restrict__ betas, float* __restrict__ betae)
{
    __shared__ float h_s[32][H_];   // 32 KB
    const int t    = threadIdx.x;
    const int lane = t & 63;
    const int wv   = t >> 6;
    const int tokBase = blockIdx.x * 32;

    {
        const float4* src = reinterpret_cast<const float4*>(hin + (long)tokBase * H_);
        float4* dst = reinterpret_cast<float4*>(&h_s[0][0]);
#pragma unroll
        for (int i = 0; i < 8; ++i) dst[t + 256*i] = src[t + 256*i];
    }
    __syncthreads();

    float a[8][4];
    {
        float b0 = bsem[lane], b1v = bsem[lane+64];
        float b2v = bepi[lane], b3v = bepi[lane+64];
#pragma unroll
        for (int i = 0; i < 8; ++i) { a[i][0]=b0; a[i][1]=b1v; a[i][2]=b2v; a[i][3]=b3v; }
    }
#pragma unroll 4
    for (int k = 0; k < H_; ++k) {
        float w0 = Wsem[k*HALF_ + lane];
        float w1 = Wsem[k*HALF_ + lane + 64];
        float w2 = Wepi[k*HALF_ + lane];
        float w3 = Wepi[k*HALF_ + lane + 64];
#pragma unroll
        for (int i = 0; i < 8; ++i) {
            float hv = h_s[wv*8 + i][k];              // broadcast
            a[i][0] = fmaf(hv, w0, a[i][0]);
            a[i][1] = fmaf(hv, w1, a[i][1]);
            a[i][2] = fmaf(hv, w2, a[i][2]);
            a[i][3] = fmaf(hv, w3, a[i][3]);
        }
    }
#pragma unroll
    for (int i = 0; i < 8; ++i) {
        const long tok = tokBase + wv*8 + i;
        ks[tok*HALF_ + lane]      = a[i][0];
        ks[tok*HALF_ + lane + 64] = a[i][1];
        ke[tok*HALF_ + lane]      = a[i][2];
        ke[tok*HALF_ + lane + 64] = a[i][3];
        float ps = wave_reduce_sum(a[i][0]*a[i][0] + a[i][1]*a[i][1]);
        float pe = wave_reduce_sum(a[i][2]*a[i][2] + a[i][3]*a[i][3]);
        if (lane == 0) {
            betas[tok] = 1.f / (ps + 1e-6f);
            betae[tok] = 1.f / (pe + 1e-6f);
        }
    }
}

// ---------------------------------------------------------------------------
// K3: backward vector scan.  M_T q = sum_t c_t k_t (k_t . w_t),
// w_{t-1} = w_t - gamma_t k_t (k_t . w_t), w_T = q.
// For M_s: c=1, gamma=beta_s.  For M_e: c=s_t, gamma=s_t*beta_e, s_t=(t+1)/512.
// One wave per batch; both chains interleaved; k prefetched one step ahead.
// ---------------------------------------------------------------------------
__global__ __launch_bounds__(64) void k_scan(
    const float* __restrict__ ks, const float* __restrict__ ke,
    const float* __restrict__ betas, const float* __restrict__ betae,
    float* __restrict__ cvec)
{
    const int b = blockIdx.x;
    const int lane = threadIdx.x;
    const float* ksb = ks + (long)b * L_ * HALF_;
    const float* keb = ke + (long)b * L_ * HALF_;
    const float* bsb = betas + b * L_;
    const float* beb = betae + b * L_;

    float ws0 = ksb[511*HALF_ + lane], ws1 = ksb[511*HALF_ + lane + 64]; // qs
    float we0 = keb[511*HALF_ + lane], we1 = keb[511*HALF_ + lane + 64]; // qe
    float as0 = 0.f, as1 = 0.f, ae0 = 0.f, ae1 = 0.f;

    float k0 = ksb[510*HALF_ + lane], k1 = ksb[510*HALF_ + lane + 64];
    float q0 = keb[510*HALF_ + lane], q1 = keb[510*HALF_ + lane + 64];

    for (int i = 510; i >= 0; --i) {
        float nk0=0.f, nk1=0.f, nq0=0.f, nq1=0.f;
        if (i > 0) {   // prefetch next step while reduce latency drains
            nk0 = ksb[(i-1)*HALF_ + lane]; nk1 = ksb[(i-1)*HALF_ + lane + 64];
            nq0 = keb[(i-1)*HALF_ + lane]; nq1 = keb[(i-1)*HALF_ + lane + 64];
        }
        const float bs = bsb[i], be = beb[i];
        const float sc = (float)(i + 1) * (1.f/512.f);

        float ds = fmaf(k0, ws0, k1 * ws1);
        float de = fmaf(q0, we0, q1 * we1);
#pragma unroll
        for (int off = 32; off > 0; off >>= 1) {
            ds += __shfl_xor(ds, off, 64);
            de += __shfl_xor(de, off, 64);
        }
        as0 = fmaf(ds, k0, as0); as1 = fmaf(ds, k1, as1);
        float gs = ds * bs;
        ws0 = fmaf(-gs, k0, ws0); ws1 = fmaf(-gs, k1, ws1);
        float cde = sc * de;
        ae0 = fmaf(cde, q0, ae0); ae1 = fmaf(cde, q1, ae1);
        float ge = cde * be;
        we0 = fmaf(-ge, q0, we0); we1 = fmaf(-ge, q1, we1);

        k0 = nk0; k1 = nk1; q0 = nq0; q1 = nq1;
    }
    float* cb = cvec + b * 256;
    cb[lane]       = as0;
    cb[lane + 64]  = as1;
    cb[lane + 128] = ae0;
    cb[lane + 192] = ae1;
}

// ---------------------------------------------------------------------------
// K4: out[64][32000] = [cs|ce] @ Wout + bout.  64 cols per block; c staged
// row-major in LDS (all inner reads are wave-uniform broadcasts).
// ---------------------------------------------------------------------------
__global__ __launch_bounds__(256) void k_out(
    const float* __restrict__ cvec, const float* __restrict__ Wout,
    const float* __restrict__ bout, float* __restrict__ out)
{
    __shared__ float c_s[64][256];   // 64 KB, [batch][dim]
    const int t = threadIdx.x;
    {
        float* flat = &c_s[0][0];
#pragma unroll
        for (int r = 0; r < 64; ++r) flat[t + r*256] = cvec[t + r*256];
    }
    __syncthreads();

    const int col = blockIdx.x * 64 + (t & 63);
    const int bg  = (t >> 6) * 16;    // 16 batches per wave
    float acc[16];
#pragma unroll
    for (int i = 0; i < 16; ++i) acc[i] = 0.f;

    for (int i = 0; i < 256; ++i) {
        float wv = Wout[(long)i*V_ + col];
#pragma unroll
        for (int bb = 0; bb < 16; ++bb)
            acc[bb] = fmaf(c_s[bg + bb][i], wv, acc[bb]);  // broadcast reads
    }
    float bo = bout[col];
#pragma unroll
    for (int bb = 0; bb < 16; ++bb)
        out[(long)(bg + bb)*V_ + col] = acc[bb] + bo;
}

// ---------------------------------------------------------------------------
extern "C" void kernel_launch(void* const* d_in, const int* in_sizes, int n_in,
                              void* d_out, int out_size, void* d_ws, size_t ws_size,
                              hipStream_t stream)
{
    (void)in_sizes; (void)n_in; (void)out_size; (void)ws_size;
    const int*   seq   = (const int*)  d_in[0];
    const float* embed = (const float*)d_in[1];
    const float* W1    = (const float*)d_in[2];
    const float* b1    = (const float*)d_in[3];
    const float* W2    = (const float*)d_in[4];
    const float* b2    = (const float*)d_in[5];
    const float* ln_g  = (const float*)d_in[6];
    const float* ln_b  = (const float*)d_in[7];
    const float* Wsem  = (const float*)d_in[8];
    const float* bsem  = (const float*)d_in[9];
    const float* Wepi  = (const float*)d_in[10];
    const float* bepi  = (const float*)d_in[11];
    const float* Wout  = (const float*)d_in[12];
    const float* bout  = (const float*)d_in[13];
    float* out = (float*)d_out;

    float* ws    = (float*)d_ws;
    float* h     = ws;                              // 32768*256
    float* ks    = h     + (size_t)NTOK_ * H_;      // 32768*128
    float* ke    = ks    + (size_t)NTOK_ * HALF_;   // 32768*128
    float* betas = ke    + (size_t)NTOK_ * HALF_;   // 32768
    float* betae = betas + NTOK_;                   // 32768
    float* cvec  = betae + NTOK_;                   // 64*256

    k_encode<<<NTOK_/32, 256, 0, stream>>>(seq, embed, W1, b1, W2, b2, ln_g, ln_b, h);
    k_proj  <<<NTOK_/32, 256, 0, stream>>>(h, Wsem, bsem, Wepi, bepi, ks, ke, betas, betae);
    k_scan  <<<B_,        64, 0, stream>>>(ks, ke, betas, betae, cvec);
    k_out   <<<V_/64,    256, 0, stream>>>(cvec, Wout, bout, out);
}

// Round 2
// 265.723 us; speedup vs baseline: 2.2317x; 2.2317x over previous
//
#include <hip/hip_runtime.h>
#include <hip/hip_bf16.h>
#include <stdint.h>

#define B_   64
#define L_   512
#define H_   256
#define H2_  512
#define HALF_ 128
#define V_   32000
#define NTOK_ (B_*L_)

typedef __attribute__((ext_vector_type(8))) short bf16x8;
typedef __attribute__((ext_vector_type(4))) float f32x4;

__device__ __forceinline__ float bf2f(short h){
    union { unsigned u; float f; } v; v.u = ((unsigned)(unsigned short)h) << 16; return v.f;
}
__device__ __forceinline__ short f2bf(float f){
    union { float f; unsigned u; } v; v.f = f;
    unsigned r = v.u + 0x7fffu + ((v.u >> 16) & 1u);   // RNE
    return (short)(r >> 16);
}
__device__ __forceinline__ float rsum64(float v){
#pragma unroll
    for (int o = 32; o > 0; o >>= 1) v += __shfl_xor(v, o, 64);
    return v;
}

// ---------------------------------------------------------------------------
// Prep: bf16-transpose weights so MFMA B-fragments are contiguous 16B loads.
// W1t [512][256], W2t [256][512], Wpt [256][256] (= [Wsem|Wepi]^T), bp [256].
// ---------------------------------------------------------------------------
__global__ __launch_bounds__(256) void k_prep(
    const float* __restrict__ W1, const float* __restrict__ W2,
    const float* __restrict__ Wsem, const float* __restrict__ Wepi,
    const float* __restrict__ bsem, const float* __restrict__ bepi,
    short* __restrict__ W1t, short* __restrict__ W2t, short* __restrict__ Wpt,
    float* __restrict__ bp)
{
    const int n = blockIdx.x, t = threadIdx.x;
    if (n < 512) {
        W1t[n*256 + t] = f2bf(W1[t*H2_ + n]);
    } else if (n < 768) {
        const int r = n - 512;
        W2t[r*512 + t]       = f2bf(W2[t*H_ + r]);
        W2t[r*512 + t + 256] = f2bf(W2[(t+256)*H_ + r]);
    } else {
        const int r = n - 768;
        Wpt[r*256 + t] = f2bf(r < 128 ? Wsem[t*HALF_ + r] : Wepi[t*HALF_ + (r-128)]);
        if (t == 0) bp[r] = (r < 128) ? bsem[r] : bepi[r-128];
    }
}

// ---------------------------------------------------------------------------
// Fused encode: gather -> GEMM1(relu) -> GEMM2 -> residual+LN -> GEMM3(proj)
// 32 tokens/block, 4 waves. A-tiles in LDS (bf16, padded rows), B direct from
// L2-resident bf16-transposed weights. MFMA 16x16x32 bf16, f32 accumulate.
// Fragment convention (consistent A/B => k-permutation cancels):
//   A: row = lane&15 (+16m), k = kk*32 + 8*(lane>>4) + i  (8 contiguous bf16)
//   B: col = lane&15,        k = same                      (from [N][K] array)
//   C: col = lane&15, row = (lane>>4)*4 + reg              (m89-verified)
// ---------------------------------------------------------------------------
#define EA_LD 264
#define FB_LD 520

__global__ __launch_bounds__(256) void k_encode_fused(
    const int* __restrict__ seq, const float* __restrict__ embed,
    const short* __restrict__ W1t, const float* __restrict__ b1,
    const short* __restrict__ W2t, const float* __restrict__ b2,
    const float* __restrict__ ln_g, const float* __restrict__ ln_b,
    const short* __restrict__ Wpt, const float* __restrict__ bp,
    float* __restrict__ kske)
{
    __shared__ __align__(16) char smem[50176];   // eA(16896)+fB(33280); hA overlays eA
    __shared__ float lnp[4][32][2];
    short* eA = (short*)smem;                    // [32][264] bf16
    short* fB = (short*)(smem + 16896);          // [32][520] bf16
    short* hA = (short*)smem;                    // [32][264] bf16 (after eA dead)

    const int tid = threadIdx.x;
    const int lo  = tid & 15;
    const int hi  = (tid >> 4) & 3;
    const int wv  = tid >> 6;
    const int tokBase = blockIdx.x * 32;

    // ---- gather embed rows (f32) -> eA (bf16) ----
    {
        const int tk = tid >> 3, part = tid & 7;
        const float4* src = (const float4*)(embed + (size_t)seq[tokBase + tk] * H_);
#pragma unroll
        for (int i = 0; i < 8; ++i) {
            float4 v = src[part + 8*i];
            short4 o; o.x = f2bf(v.x); o.y = f2bf(v.y); o.z = f2bf(v.z); o.w = f2bf(v.w);
            *(short4*)&eA[tk*EA_LD + (part + 8*i)*4] = o;
        }
    }
    __syncthreads();

    // ---- GEMM1: ff1 = e @ W1, wave owns N-slice of 128 (of 512) ----
    f32x4 acc1[2][8];
#pragma unroll
    for (int m = 0; m < 2; ++m)
#pragma unroll
        for (int nf = 0; nf < 8; ++nf) acc1[m][nf] = (f32x4){0.f,0.f,0.f,0.f};
    {
        const int n0 = wv * 128;
#pragma unroll
        for (int kk = 0; kk < 8; ++kk) {
            const int k0 = kk*32 + 8*hi;
            bf16x8 a0 = *(const bf16x8*)&eA[(lo     )*EA_LD + k0];
            bf16x8 a1 = *(const bf16x8*)&eA[(lo + 16)*EA_LD + k0];
#pragma unroll
            for (int nf = 0; nf < 8; ++nf) {
                bf16x8 b = *(const bf16x8*)(W1t + (size_t)(n0 + nf*16 + lo)*256 + k0);
                acc1[0][nf] = __builtin_amdgcn_mfma_f32_16x16x32_bf16(a0, b, acc1[0][nf], 0,0,0);
                acc1[1][nf] = __builtin_amdgcn_mfma_f32_16x16x32_bf16(a1, b, acc1[1][nf], 0,0,0);
            }
        }
        // bias + relu -> fB (bf16)
#pragma unroll
        for (int nf = 0; nf < 8; ++nf) {
            const int col = n0 + nf*16 + lo;
            const float bb = b1[col];
#pragma unroll
            for (int m = 0; m < 2; ++m)
#pragma unroll
                for (int r = 0; r < 4; ++r) {
                    const int row = m*16 + hi*4 + r;
                    fB[row*FB_LD + col] = f2bf(fmaxf(acc1[m][nf][r] + bb, 0.f));
                }
        }
    }
    __syncthreads();

    // ---- GEMM2: ff2 = ff1 @ W2, wave owns N-slice of 64 (of 256) ----
    f32x4 acc2[2][4];
#pragma unroll
    for (int m = 0; m < 2; ++m)
#pragma unroll
        for (int nf = 0; nf < 4; ++nf) acc2[m][nf] = (f32x4){0.f,0.f,0.f,0.f};
    {
        const int n0 = wv * 64;
#pragma unroll
        for (int kk = 0; kk < 16; ++kk) {
            const int k0 = kk*32 + 8*hi;
            bf16x8 a0 = *(const bf16x8*)&fB[(lo     )*FB_LD + k0];
            bf16x8 a1 = *(const bf16x8*)&fB[(lo + 16)*FB_LD + k0];
#pragma unroll
            for (int nf = 0; nf < 4; ++nf) {
                bf16x8 b = *(const bf16x8*)(W2t + (size_t)(n0 + nf*16 + lo)*512 + k0);
                acc2[0][nf] = __builtin_amdgcn_mfma_f32_16x16x32_bf16(a0, b, acc2[0][nf], 0,0,0);
                acc2[1][nf] = __builtin_amdgcn_mfma_f32_16x16x32_bf16(a1, b, acc2[1][nf], 0,0,0);
            }
        }
    }

    // ---- x = e + ff2 + b2 ; LN partial sums ----
    {
        const int n0 = wv * 64;
#pragma unroll
        for (int nf = 0; nf < 4; ++nf) {
            const int col = n0 + nf*16 + lo;
            const float bb = b2[col];
#pragma unroll
            for (int m = 0; m < 2; ++m)
#pragma unroll
                for (int r = 0; r < 4; ++r) {
                    const int row = m*16 + hi*4 + r;
                    acc2[m][nf][r] += bb + bf2f(eA[row*EA_LD + col]);
                }
        }
#pragma unroll
        for (int m = 0; m < 2; ++m)
#pragma unroll
            for (int r = 0; r < 4; ++r) {
                float s = 0.f, s2 = 0.f;
#pragma unroll
                for (int nf = 0; nf < 4; ++nf) { float xv = acc2[m][nf][r]; s += xv; s2 = fmaf(xv, xv, s2); }
#pragma unroll
                for (int o = 1; o < 16; o <<= 1) { s += __shfl_xor(s, o, 64); s2 += __shfl_xor(s2, o, 64); }
                if (lo == 0) { const int row = m*16 + hi*4 + r; lnp[wv][row][0] = s; lnp[wv][row][1] = s2; }
            }
    }
    __syncthreads();   // eA reads done + lnp visible

    // ---- combine LN stats, normalize, write hA (overlays eA) ----
    {
        const int n0 = wv * 64;
        float gv[4], bv[4];
#pragma unroll
        for (int nf = 0; nf < 4; ++nf) { const int col = n0 + nf*16 + lo; gv[nf] = ln_g[col]; bv[nf] = ln_b[col]; }
#pragma unroll
        for (int m = 0; m < 2; ++m)
#pragma unroll
            for (int r = 0; r < 4; ++r) {
                const int row = m*16 + hi*4 + r;
                float s  = lnp[0][row][0] + lnp[1][row][0] + lnp[2][row][0] + lnp[3][row][0];
                float s2 = lnp[0][row][1] + lnp[1][row][1] + lnp[2][row][1] + lnp[3][row][1];
                float mu   = s * (1.f/256.f);
                float var  = s2 * (1.f/256.f) - mu*mu;
                float rstd = rsqrtf(var + 1e-5f);
#pragma unroll
                for (int nf = 0; nf < 4; ++nf) {
                    const int col = n0 + nf*16 + lo;
                    hA[row*EA_LD + col] = f2bf((acc2[m][nf][r] - mu) * rstd * gv[nf] + bv[nf]);
                }
            }
    }
    __syncthreads();

    // ---- GEMM3: [ks|ke] = h @ [Wsem|Wepi] + bp -> global f32 ----
    f32x4 acc3[2][4];
#pragma unroll
    for (int m = 0; m < 2; ++m)
#pragma unroll
        for (int nf = 0; nf < 4; ++nf) acc3[m][nf] = (f32x4){0.f,0.f,0.f,0.f};
    {
        const int n0 = wv * 64;
#pragma unroll
        for (int kk = 0; kk < 8; ++kk) {
            const int k0 = kk*32 + 8*hi;
            bf16x8 a0 = *(const bf16x8*)&hA[(lo     )*EA_LD + k0];
            bf16x8 a1 = *(const bf16x8*)&hA[(lo + 16)*EA_LD + k0];
#pragma unroll
            for (int nf = 0; nf < 4; ++nf) {
                bf16x8 b = *(const bf16x8*)(Wpt + (size_t)(n0 + nf*16 + lo)*256 + k0);
                acc3[0][nf] = __builtin_amdgcn_mfma_f32_16x16x32_bf16(a0, b, acc3[0][nf], 0,0,0);
                acc3[1][nf] = __builtin_amdgcn_mfma_f32_16x16x32_bf16(a1, b, acc3[1][nf], 0,0,0);
            }
        }
#pragma unroll
        for (int nf = 0; nf < 4; ++nf) {
            const int col = n0 + nf*16 + lo;
            const float bb = bp[col];
#pragma unroll
            for (int m = 0; m < 2; ++m)
#pragma unroll
                for (int r = 0; r < 4; ++r) {
                    const int row = m*16 + hi*4 + r;
                    kske[(size_t)(tokBase + row)*256 + col] = acc3[m][nf][r] + bb;
                }
        }
    }
}

// ---------------------------------------------------------------------------
// K3: backward vector scan, one wave per (batch, chain). 8-deep register ring
// prefetch; beta computed on-the-fly from prefetched k (off critical path).
// dims: lane holds 2*lane, 2*lane+1.
// ---------------------------------------------------------------------------
__global__ __launch_bounds__(64) void k_scan(
    const float* __restrict__ kske, float* __restrict__ cvec)
{
    const int b = blockIdx.x;
    const int chain = blockIdx.y;        // 0 = s (cols 0..127), 1 = e (cols 128..255)
    const int lane = threadIdx.x;
    const float* base = kske + ((size_t)b * L_) * 256 + chain * HALF_ + 2*lane;

    float2 w = *(const float2*)(base + (size_t)511 * 256);   // q projection
    float a0 = 0.f, a1 = 0.f;

    float2 buf[8]; float bss[8];
#pragma unroll
    for (int s = 0; s < 8; ++s) buf[s] = *(const float2*)(base + (size_t)(510 - s) * 256);
#pragma unroll
    for (int s = 0; s < 2; ++s) bss[s] = 1.f / (rsum64(buf[s].x*buf[s].x + buf[s].y*buf[s].y) + 1e-6f);

    int j = 0;
    for (int blk = 0; blk < 63; ++blk) {
#pragma unroll
        for (int ss = 0; ss < 8; ++ss) {
            const int t = 510 - j;
            const float2 kv = buf[ss];
            const float beta = bss[ss];
            if (t >= 8) buf[ss] = *(const float2*)(base + (size_t)(t - 8) * 256);
            {   // beta for the value consumed 2 steps from now (already arrived)
                const int s2 = (ss + 2) & 7;
                const float2 kb = buf[s2];
                bss[s2] = 1.f / (rsum64(kb.x*kb.x + kb.y*kb.y) + 1e-6f);
            }
            float d = rsum64(kv.x*w.x + kv.y*w.y);
            const float sc = (float)(t + 1) * (1.f/512.f);
            const float cd = chain ? sc * d : d;
            a0 = fmaf(cd, kv.x, a0); a1 = fmaf(cd, kv.y, a1);
            const float g = cd * beta;
            w.x = fmaf(-g, kv.x, w.x); w.y = fmaf(-g, kv.y, w.y);
            ++j;
        }
    }
#pragma unroll
    for (int ss = 0; ss < 7; ++ss) {     // j = 504..510, t = 6..0
        const int t = 6 - ss;
        const float2 kv = buf[ss];
        const float beta = bss[ss];
        {
            const int s2 = (ss + 2) & 7;
            const float2 kb = buf[s2];
            bss[s2] = 1.f / (rsum64(kb.x*kb.x + kb.y*kb.y) + 1e-6f);
        }
        float d = rsum64(kv.x*w.x + kv.y*w.y);
        const float sc = (float)(t + 1) * (1.f/512.f);
        const float cd = chain ? sc * d : d;
        a0 = fmaf(cd, kv.x, a0); a1 = fmaf(cd, kv.y, a1);
        const float g = cd * beta;
        w.x = fmaf(-g, kv.x, w.x); w.y = fmaf(-g, kv.y, w.y);
    }
    float2 outv; outv.x = a0; outv.y = a1;
    *(float2*)(cvec + b*256 + chain*HALF_ + 2*lane) = outv;
}

// ---------------------------------------------------------------------------
// K4: out[64][32000] = [cs|ce] @ Wout + bout
// ---------------------------------------------------------------------------
__global__ __launch_bounds__(256) void k_out(
    const float* __restrict__ cvec, const float* __restrict__ Wout,
    const float* __restrict__ bout, float* __restrict__ out)
{
    __shared__ float c_s[64][256];
    const int t = threadIdx.x;
    {
        float* flat = &c_s[0][0];
#pragma unroll
        for (int r = 0; r < 64; ++r) flat[t + r*256] = cvec[t + r*256];
    }
    __syncthreads();

    const int col = blockIdx.x * 64 + (t & 63);
    const int bg  = (t >> 6) * 16;
    float acc[16];
#pragma unroll
    for (int i = 0; i < 16; ++i) acc[i] = 0.f;

    for (int i = 0; i < 256; ++i) {
        float wv = Wout[(size_t)i*V_ + col];
#pragma unroll
        for (int bb = 0; bb < 16; ++bb)
            acc[bb] = fmaf(c_s[bg + bb][i], wv, acc[bb]);
    }
    float bo = bout[col];
#pragma unroll
    for (int bb = 0; bb < 16; ++bb)
        out[(size_t)(bg + bb)*V_ + col] = acc[bb] + bo;
}

// ---------------------------------------------------------------------------
extern "C" void kernel_launch(void* const* d_in, const int* in_sizes, int n_in,
                              void* d_out, int out_size, void* d_ws, size_t ws_size,
                              hipStream_t stream)
{
    (void)in_sizes; (void)n_in; (void)out_size; (void)ws_size;
    const int*   seq   = (const int*)  d_in[0];
    const float* embed = (const float*)d_in[1];
    const float* W1    = (const float*)d_in[2];
    const float* b1    = (const float*)d_in[3];
    const float* W2    = (const float*)d_in[4];
    const float* b2    = (const float*)d_in[5];
    const float* ln_g  = (const float*)d_in[6];
    const float* ln_b  = (const float*)d_in[7];
    const float* Wsem  = (const float*)d_in[8];
    const float* bsem  = (const float*)d_in[9];
    const float* Wepi  = (const float*)d_in[10];
    const float* bepi  = (const float*)d_in[11];
    const float* Wout  = (const float*)d_in[12];
    const float* bout  = (const float*)d_in[13];
    float* out = (float*)d_out;

    char* wp = (char*)d_ws;
    short* W1t = (short*)wp;  wp += (size_t)512*256*2;
    short* W2t = (short*)wp;  wp += (size_t)256*512*2;
    short* Wpt = (short*)wp;  wp += (size_t)256*256*2;
    float* bp  = (float*)wp;  wp += 256*4;
    float* kske= (float*)wp;  wp += (size_t)NTOK_*256*4;
    float* cvec= (float*)wp;

    k_prep<<<1024, 256, 0, stream>>>(W1, W2, Wsem, Wepi, bsem, bepi, W1t, W2t, Wpt, bp);
    k_encode_fused<<<NTOK_/32, 256, 0, stream>>>(seq, embed, W1t, b1, W2t, b2,
                                                 ln_g, ln_b, Wpt, bp, kske);
    k_scan<<<dim3(B_, 2), 64, 0, stream>>>(kske, cvec);
    k_out<<<V_/64, 256, 0, stream>>>(cvec, Wout, bout, out);
}

// Round 3
// 165.910 us; speedup vs baseline: 3.5742x; 1.6016x over previous
//
#include <hip/hip_runtime.h>
#include <hip/hip_bf16.h>
#include <stdint.h>

#define B_   64
#define L_   512
#define H_   256
#define H2_  512
#define HALF_ 128
#define V_   32000
#define NTOK_ (B_*L_)

typedef __attribute__((ext_vector_type(8))) short bf16x8;
typedef __attribute__((ext_vector_type(4))) float f32x4;

__device__ __forceinline__ float bf2f(short h){
    union { unsigned u; float f; } v; v.u = ((unsigned)(unsigned short)h) << 16; return v.f;
}
__device__ __forceinline__ short f2bf(float f){
    union { float f; unsigned u; } v; v.f = f;
    unsigned r = v.u + 0x7fffu + ((v.u >> 16) & 1u);   // RNE
    return (short)(r >> 16);
}

// ---------------------------------------------------------------------------
// Prep: bf16-transpose weights so MFMA B-fragments are contiguous 16B loads.
// ---------------------------------------------------------------------------
__global__ __launch_bounds__(256) void k_prep(
    const float* __restrict__ W1, const float* __restrict__ W2,
    const float* __restrict__ Wsem, const float* __restrict__ Wepi,
    const float* __restrict__ bsem, const float* __restrict__ bepi,
    short* __restrict__ W1t, short* __restrict__ W2t, short* __restrict__ Wpt,
    float* __restrict__ bp)
{
    const int n = blockIdx.x, t = threadIdx.x;
    if (n < 512) {
        W1t[n*256 + t] = f2bf(W1[t*H2_ + n]);
    } else if (n < 768) {
        const int r = n - 512;
        W2t[r*512 + t]       = f2bf(W2[t*H_ + r]);
        W2t[r*512 + t + 256] = f2bf(W2[(t+256)*H_ + r]);
    } else {
        const int r = n - 768;
        Wpt[r*256 + t] = f2bf(r < 128 ? Wsem[t*HALF_ + r] : Wepi[t*HALF_ + (r-128)]);
        if (t == 0) bp[r] = (r < 128) ? bsem[r] : bepi[r-128];
    }
}

// ---------------------------------------------------------------------------
// Fused encode: gather -> GEMM1(relu) -> GEMM2 -> residual+LN -> GEMM3(proj)
// (unchanged from round 1 — verified)
// ---------------------------------------------------------------------------
#define EA_LD 264
#define FB_LD 520

__global__ __launch_bounds__(256) void k_encode_fused(
    const int* __restrict__ seq, const float* __restrict__ embed,
    const short* __restrict__ W1t, const float* __restrict__ b1,
    const short* __restrict__ W2t, const float* __restrict__ b2,
    const float* __restrict__ ln_g, const float* __restrict__ ln_b,
    const short* __restrict__ Wpt, const float* __restrict__ bp,
    float* __restrict__ kske)
{
    __shared__ __align__(16) char smem[50176];
    __shared__ float lnp[4][32][2];
    short* eA = (short*)smem;                    // [32][264] bf16
    short* fB = (short*)(smem + 16896);          // [32][520] bf16
    short* hA = (short*)smem;                    // overlays eA

    const int tid = threadIdx.x;
    const int lo  = tid & 15;
    const int hi  = (tid >> 4) & 3;
    const int wv  = tid >> 6;
    const int tokBase = blockIdx.x * 32;

    {
        const int tk = tid >> 3, part = tid & 7;
        const float4* src = (const float4*)(embed + (size_t)seq[tokBase + tk] * H_);
#pragma unroll
        for (int i = 0; i < 8; ++i) {
            float4 v = src[part + 8*i];
            short4 o; o.x = f2bf(v.x); o.y = f2bf(v.y); o.z = f2bf(v.z); o.w = f2bf(v.w);
            *(short4*)&eA[tk*EA_LD + (part + 8*i)*4] = o;
        }
    }
    __syncthreads();

    f32x4 acc1[2][8];
#pragma unroll
    for (int m = 0; m < 2; ++m)
#pragma unroll
        for (int nf = 0; nf < 8; ++nf) acc1[m][nf] = (f32x4){0.f,0.f,0.f,0.f};
    {
        const int n0 = wv * 128;
#pragma unroll
        for (int kk = 0; kk < 8; ++kk) {
            const int k0 = kk*32 + 8*hi;
            bf16x8 a0 = *(const bf16x8*)&eA[(lo     )*EA_LD + k0];
            bf16x8 a1 = *(const bf16x8*)&eA[(lo + 16)*EA_LD + k0];
#pragma unroll
            for (int nf = 0; nf < 8; ++nf) {
                bf16x8 b = *(const bf16x8*)(W1t + (size_t)(n0 + nf*16 + lo)*256 + k0);
                acc1[0][nf] = __builtin_amdgcn_mfma_f32_16x16x32_bf16(a0, b, acc1[0][nf], 0,0,0);
                acc1[1][nf] = __builtin_amdgcn_mfma_f32_16x16x32_bf16(a1, b, acc1[1][nf], 0,0,0);
            }
        }
#pragma unroll
        for (int nf = 0; nf < 8; ++nf) {
            const int col = n0 + nf*16 + lo;
            const float bb = b1[col];
#pragma unroll
            for (int m = 0; m < 2; ++m)
#pragma unroll
                for (int r = 0; r < 4; ++r) {
                    const int row = m*16 + hi*4 + r;
                    fB[row*FB_LD + col] = f2bf(fmaxf(acc1[m][nf][r] + bb, 0.f));
                }
        }
    }
    __syncthreads();

    f32x4 acc2[2][4];
#pragma unroll
    for (int m = 0; m < 2; ++m)
#pragma unroll
        for (int nf = 0; nf < 4; ++nf) acc2[m][nf] = (f32x4){0.f,0.f,0.f,0.f};
    {
        const int n0 = wv * 64;
#pragma unroll
        for (int kk = 0; kk < 16; ++kk) {
            const int k0 = kk*32 + 8*hi;
            bf16x8 a0 = *(const bf16x8*)&fB[(lo     )*FB_LD + k0];
            bf16x8 a1 = *(const bf16x8*)&fB[(lo + 16)*FB_LD + k0];
#pragma unroll
            for (int nf = 0; nf < 4; ++nf) {
                bf16x8 b = *(const bf16x8*)(W2t + (size_t)(n0 + nf*16 + lo)*512 + k0);
                acc2[0][nf] = __builtin_amdgcn_mfma_f32_16x16x32_bf16(a0, b, acc2[0][nf], 0,0,0);
                acc2[1][nf] = __builtin_amdgcn_mfma_f32_16x16x32_bf16(a1, b, acc2[1][nf], 0,0,0);
            }
        }
    }

    {
        const int n0 = wv * 64;
#pragma unroll
        for (int nf = 0; nf < 4; ++nf) {
            const int col = n0 + nf*16 + lo;
            const float bb = b2[col];
#pragma unroll
            for (int m = 0; m < 2; ++m)
#pragma unroll
                for (int r = 0; r < 4; ++r) {
                    const int row = m*16 + hi*4 + r;
                    acc2[m][nf][r] += bb + bf2f(eA[row*EA_LD + col]);
                }
        }
#pragma unroll
        for (int m = 0; m < 2; ++m)
#pragma unroll
            for (int r = 0; r < 4; ++r) {
                float s = 0.f, s2 = 0.f;
#pragma unroll
                for (int nf = 0; nf < 4; ++nf) { float xv = acc2[m][nf][r]; s += xv; s2 = fmaf(xv, xv, s2); }
#pragma unroll
                for (int o = 1; o < 16; o <<= 1) { s += __shfl_xor(s, o, 64); s2 += __shfl_xor(s2, o, 64); }
                if (lo == 0) { const int row = m*16 + hi*4 + r; lnp[wv][row][0] = s; lnp[wv][row][1] = s2; }
            }
    }
    __syncthreads();

    {
        const int n0 = wv * 64;
        float gv[4], bv[4];
#pragma unroll
        for (int nf = 0; nf < 4; ++nf) { const int col = n0 + nf*16 + lo; gv[nf] = ln_g[col]; bv[nf] = ln_b[col]; }
#pragma unroll
        for (int m = 0; m < 2; ++m)
#pragma unroll
            for (int r = 0; r < 4; ++r) {
                const int row = m*16 + hi*4 + r;
                float s  = lnp[0][row][0] + lnp[1][row][0] + lnp[2][row][0] + lnp[3][row][0];
                float s2 = lnp[0][row][1] + lnp[1][row][1] + lnp[2][row][1] + lnp[3][row][1];
                float mu   = s * (1.f/256.f);
                float var  = s2 * (1.f/256.f) - mu*mu;
                float rstd = rsqrtf(var + 1e-5f);
#pragma unroll
                for (int nf = 0; nf < 4; ++nf) {
                    const int col = n0 + nf*16 + lo;
                    hA[row*EA_LD + col] = f2bf((acc2[m][nf][r] - mu) * rstd * gv[nf] + bv[nf]);
                }
            }
    }
    __syncthreads();

    f32x4 acc3[2][4];
#pragma unroll
    for (int m = 0; m < 2; ++m)
#pragma unroll
        for (int nf = 0; nf < 4; ++nf) acc3[m][nf] = (f32x4){0.f,0.f,0.f,0.f};
    {
        const int n0 = wv * 64;
#pragma unroll
        for (int kk = 0; kk < 8; ++kk) {
            const int k0 = kk*32 + 8*hi;
            bf16x8 a0 = *(const bf16x8*)&hA[(lo     )*EA_LD + k0];
            bf16x8 a1 = *(const bf16x8*)&hA[(lo + 16)*EA_LD + k0];
#pragma unroll
            for (int nf = 0; nf < 4; ++nf) {
                bf16x8 b = *(const bf16x8*)(Wpt + (size_t)(n0 + nf*16 + lo)*256 + k0);
                acc3[0][nf] = __builtin_amdgcn_mfma_f32_16x16x32_bf16(a0, b, acc3[0][nf], 0,0,0);
                acc3[1][nf] = __builtin_amdgcn_mfma_f32_16x16x32_bf16(a1, b, acc3[1][nf], 0,0,0);
            }
        }
#pragma unroll
        for (int nf = 0; nf < 4; ++nf) {
            const int col = n0 + nf*16 + lo;
            const float bb = bp[col];
#pragma unroll
            for (int m = 0; m < 2; ++m)
#pragma unroll
                for (int r = 0; r < 4; ++r) {
                    const int row = m*16 + hi*4 + r;
                    kske[(size_t)(tokBase + row)*256 + col] = acc3[m][nf][r] + bb;
                }
        }
    }
}

// ---------------------------------------------------------------------------
// k_gram: per (batch, chain, chunk of 16 tokens) compute the 16x16 Gram
// G_ij = k_i . k_j via split-bf16 MFMA (f32-accurate), derive beta from diag,
// fold gamma (and the t=511 zero-pad) in, and store PRE-NEGATED column-scaled
// G' = -gamma_j * G_ij, row-major, plus -gamma vector.
// ---------------------------------------------------------------------------
__global__ __launch_bounds__(64) void k_gram(
    const float* __restrict__ kske, float* __restrict__ Gp, float* __restrict__ gv)
{
    const int c = blockIdx.x, chain = blockIdx.y, b = blockIdx.z;
    const int l = threadIdx.x, lo = l & 15, hi = l >> 4;
    const size_t rowbase = ((size_t)(b*L_ + c*16 + lo))*256 + chain*HALF_ + 8*hi;

    bf16x8 ah[4], al[4];
#pragma unroll
    for (int m = 0; m < 4; ++m) {
        float4 v0 = *(const float4*)(kske + rowbase + m*32);
        float4 v1 = *(const float4*)(kske + rowbase + m*32 + 4);
        float f[8] = {v0.x,v0.y,v0.z,v0.w,v1.x,v1.y,v1.z,v1.w};
#pragma unroll
        for (int i = 0; i < 8; ++i) {
            short h = f2bf(f[i]);
            ah[m][i] = h;
            al[m][i] = f2bf(f[i] - bf2f(h));
        }
    }
    f32x4 g = {0.f,0.f,0.f,0.f};
#pragma unroll
    for (int m = 0; m < 4; ++m) {
        g = __builtin_amdgcn_mfma_f32_16x16x32_bf16(ah[m], ah[m], g, 0,0,0);
        g = __builtin_amdgcn_mfma_f32_16x16x32_bf16(ah[m], al[m], g, 0,0,0);
        g = __builtin_amdgcn_mfma_f32_16x16x32_bf16(al[m], ah[m], g, 0,0,0);
    }
    // diagonal -> beta (lane layout: col=lo, row=4*hi+r)
    __shared__ float diag[16];
#pragma unroll
    for (int r = 0; r < 4; ++r)
        if (4*hi + r == lo) diag[lo] = g[r];
    __syncthreads();
    const int tcol = c*16 + lo;
    float beta = 1.f / (diag[lo] + 1e-6f);
    float gam  = chain ? ((float)(tcol+1) * (1.f/512.f)) * beta : beta;
    if (tcol == 511) gam = 0.f;      // q token: no update, no contribution
    const size_t gbase = ((size_t)((b*2 + chain)*32 + c))*256;
#pragma unroll
    for (int r = 0; r < 4; ++r)
        Gp[gbase + (size_t)(4*hi+r)*16 + lo] = -gam * g[r];
    if (l < 16) gv[((b*2 + chain)*32 + c)*16 + lo] = -gam;
}

// ---------------------------------------------------------------------------
// k_scan: chunked WY backward scan. One wave per (batch, chain).
// Per 16-token chunk: b = K.w_top (LDS-broadcast w, 32-fma GEMV, 2 shfl),
// then 16 scalar solve steps: readlane(d_j) -> fmac (VALU-only critical path),
// accumulating w and the answer a in-register. Gram rows/k prefetched 1 chunk
// ahead (double-buffered, static indexing via macro).
// ---------------------------------------------------------------------------
#define SCAN_BODY(CC, GA, KXA, KYA, NGA, GB, KXB, KYB, NGB) do {              \
    const int c_ = (CC);                                                      \
    wls[2*l] = w.x; wls[2*l+1] = w.y;                                         \
    float p0=0.f, p1=0.f, p2=0.f, p3=0.f;                                     \
    _Pragma("unroll")                                                         \
    for (int i = 0; i < 8; ++i) {                                             \
        float4 wv = *(const float4*)&wls[q*32 + 4*i];                         \
        p0 = fmaf(kq[i].x, wv.x, p0); p1 = fmaf(kq[i].y, wv.y, p1);           \
        p2 = fmaf(kq[i].z, wv.z, p2); p3 = fmaf(kq[i].w, wv.w, p3);           \
    }                                                                         \
    float bb = (p0 + p1) + (p2 + p3);                                         \
    bb += __shfl_xor(bb, 16, 64);                                             \
    bb += __shfl_xor(bb, 32, 64);                                             \
    if (c_ > 0) {                                                             \
        const float* krow = kb + ((size_t)((c_-1)*16 + lo))*256 + q*32;       \
        _Pragma("unroll")                                                     \
        for (int i = 0; i < 8; ++i) kq[i] = *(const float4*)(krow + 4*i);     \
        const float* gr = gpb + (size_t)(c_-1)*256 + lo*16;                   \
        _Pragma("unroll")                                                     \
        for (int i = 0; i < 4; ++i) {                                         \
            float4 gt = *(const float4*)(gr + 4*i);                           \
            GB[4*i]=gt.x; GB[4*i+1]=gt.y; GB[4*i+2]=gt.z; GB[4*i+3]=gt.w;     \
        }                                                                     \
        NGB = gvb[(c_-1)*16 + lo];                                            \
        const float* kdr = kb + ((size_t)((c_-1)*16))*256 + 2*l;              \
        _Pragma("unroll")                                                     \
        for (int j = 0; j < 16; ++j) {                                        \
            float2 kt = *(const float2*)(kdr + (size_t)j*256);                \
            KXB[j] = kt.x; KYB[j] = kt.y;                                     \
        }                                                                     \
    }                                                                         \
    const int tl_ = c_*16 + lo;                                               \
    const float cl_ = chain ? ((tl_ < 511) ? (float)(tl_+1)*(1.f/512.f) : 0.f)\
                            : ((tl_ < 511) ? 1.f : 0.f);                      \
    _Pragma("unroll")                                                         \
    for (int j = 15; j >= 0; --j) {                                           \
        float dj = __int_as_float(__builtin_amdgcn_readlane(__float_as_int(bb), j)); \
        bb = fmaf(dj, GA[j], bb);                                             \
        float tg = NGA * dj;                                                  \
        float tc = cl_ * dj;                                                  \
        float gd = __int_as_float(__builtin_amdgcn_readlane(__float_as_int(tg), j)); \
        float cd = __int_as_float(__builtin_amdgcn_readlane(__float_as_int(tc), j)); \
        w.x = fmaf(gd, KXA[j], w.x);  w.y = fmaf(gd, KYA[j], w.y);            \
        ax  = fmaf(cd, KXA[j], ax);   ay  = fmaf(cd, KYA[j], ay);             \
    }                                                                         \
} while (0)

__global__ __launch_bounds__(64) void k_scan(
    const float* __restrict__ kske, const float* __restrict__ Gp,
    const float* __restrict__ gv, float* __restrict__ cvec)
{
    __shared__ float wls[128];
    const int b = blockIdx.x, chain = blockIdx.y;
    const int l = threadIdx.x, lo = l & 15, q = l >> 4;
    const float* kb  = kske + ((size_t)b*L_)*256 + chain*HALF_;
    const float* gpb = Gp + ((size_t)((b*2+chain)*32))*256;
    const float* gvb = gv + ((b*2+chain)*32)*16;

    float2 w = *(const float2*)(kb + (size_t)511*256 + 2*l);   // w_T = q
    float ax = 0.f, ay = 0.f;

    float ga[16], kxa[16], kya[16], nga;
    float gb_[16], kxb[16], kyb[16], ngb;
    float4 kq[8];

    // prologue: chunk 31 into A-buffers
    {
        const float* krow = kb + ((size_t)(31*16 + lo))*256 + q*32;
#pragma unroll
        for (int i = 0; i < 8; ++i) kq[i] = *(const float4*)(krow + 4*i);
        const float* gr = gpb + (size_t)31*256 + lo*16;
#pragma unroll
        for (int i = 0; i < 4; ++i) {
            float4 gt = *(const float4*)(gr + 4*i);
            ga[4*i]=gt.x; ga[4*i+1]=gt.y; ga[4*i+2]=gt.z; ga[4*i+3]=gt.w;
        }
        nga = gvb[31*16 + lo];
        const float* kdr = kb + ((size_t)(31*16))*256 + 2*l;
#pragma unroll
        for (int j = 0; j < 16; ++j) {
            float2 kt = *(const float2*)(kdr + (size_t)j*256);
            kxa[j] = kt.x; kya[j] = kt.y;
        }
    }

    for (int it = 0; it < 16; ++it) {
        SCAN_BODY(31 - 2*it, ga,  kxa, kya, nga, gb_, kxb, kyb, ngb);
        SCAN_BODY(30 - 2*it, gb_, kxb, kyb, ngb, ga,  kxa, kya, nga);
    }

    float2 outv; outv.x = ax; outv.y = ay;
    *(float2*)(cvec + b*256 + chain*HALF_ + 2*l) = outv;
}

// ---------------------------------------------------------------------------
// K4: out[64][32000] = [cs|ce] @ Wout + bout (unchanged)
// ---------------------------------------------------------------------------
__global__ __launch_bounds__(256) void k_out(
    const float* __restrict__ cvec, const float* __restrict__ Wout,
    const float* __restrict__ bout, float* __restrict__ out)
{
    __shared__ float c_s[64][256];
    const int t = threadIdx.x;
    {
        float* flat = &c_s[0][0];
#pragma unroll
        for (int r = 0; r < 64; ++r) flat[t + r*256] = cvec[t + r*256];
    }
    __syncthreads();

    const int col = blockIdx.x * 64 + (t & 63);
    const int bg  = (t >> 6) * 16;
    float acc[16];
#pragma unroll
    for (int i = 0; i < 16; ++i) acc[i] = 0.f;

    for (int i = 0; i < 256; ++i) {
        float wv = Wout[(size_t)i*V_ + col];
#pragma unroll
        for (int bb = 0; bb < 16; ++bb)
            acc[bb] = fmaf(c_s[bg + bb][i], wv, acc[bb]);
    }
    float bo = bout[col];
#pragma unroll
    for (int bb = 0; bb < 16; ++bb)
        out[(size_t)(bg + bb)*V_ + col] = acc[bb] + bo;
}

// ---------------------------------------------------------------------------
extern "C" void kernel_launch(void* const* d_in, const int* in_sizes, int n_in,
                              void* d_out, int out_size, void* d_ws, size_t ws_size,
                              hipStream_t stream)
{
    (void)in_sizes; (void)n_in; (void)out_size; (void)ws_size;
    const int*   seq   = (const int*)  d_in[0];
    const float* embed = (const float*)d_in[1];
    const float* W1    = (const float*)d_in[2];
    const float* b1    = (const float*)d_in[3];
    const float* W2    = (const float*)d_in[4];
    const float* b2    = (const float*)d_in[5];
    const float* ln_g  = (const float*)d_in[6];
    const float* ln_b  = (const float*)d_in[7];
    const float* Wsem  = (const float*)d_in[8];
    const float* bsem  = (const float*)d_in[9];
    const float* Wepi  = (const float*)d_in[10];
    const float* bepi  = (const float*)d_in[11];
    const float* Wout  = (const float*)d_in[12];
    const float* bout  = (const float*)d_in[13];
    float* out = (float*)d_out;

    char* wp = (char*)d_ws;
    short* W1t = (short*)wp;  wp += (size_t)512*256*2;
    short* W2t = (short*)wp;  wp += (size_t)256*512*2;
    short* Wpt = (short*)wp;  wp += (size_t)256*256*2;
    float* bp  = (float*)wp;  wp += 256*4;
    float* kske= (float*)wp;  wp += (size_t)NTOK_*256*4;
    float* Gp  = (float*)wp;  wp += (size_t)128*32*256*4;
    float* gv  = (float*)wp;  wp += (size_t)128*32*16*4;
    float* cvec= (float*)wp;

    k_prep<<<1024, 256, 0, stream>>>(W1, W2, Wsem, Wepi, bsem, bepi, W1t, W2t, Wpt, bp);
    k_encode_fused<<<NTOK_/32, 256, 0, stream>>>(seq, embed, W1t, b1, W2t, b2,
                                                 ln_g, ln_b, Wpt, bp, kske);
    k_gram<<<dim3(32, 2, B_), 64, 0, stream>>>(kske, Gp, gv);
    k_scan<<<dim3(B_, 2), 64, 0, stream>>>(kske, Gp, gv, cvec);
    k_out<<<V_/64, 256, 0, stream>>>(cvec, Wout, bout, out);
}

// Round 4
// 132.797 us; speedup vs baseline: 4.4655x; 1.2494x over previous
//
#include <hip/hip_runtime.h>
#include <hip/hip_bf16.h>
#include <stdint.h>

#define B_   64
#define L_   512
#define H_   256
#define H2_  512
#define HALF_ 128
#define V_   32000
#define NTOK_ (B_*L_)

typedef __attribute__((ext_vector_type(8))) short bf16x8;
typedef __attribute__((ext_vector_type(4))) float f32x4;

__device__ __forceinline__ float bf2f(short h){
    union { unsigned u; float f; } v; v.u = ((unsigned)(unsigned short)h) << 16; return v.f;
}
__device__ __forceinline__ short f2bf(float f){
    union { float f; unsigned u; } v; v.f = f;
    unsigned r = v.u + 0x7fffu + ((v.u >> 16) & 1u);   // RNE
    return (short)(r >> 16);
}

// ---------------------------------------------------------------------------
// Prep: bf16-transpose weights so MFMA B-fragments are contiguous 16B loads.
// ---------------------------------------------------------------------------
__global__ __launch_bounds__(256) void k_prep(
    const float* __restrict__ W1, const float* __restrict__ W2,
    const float* __restrict__ Wsem, const float* __restrict__ Wepi,
    const float* __restrict__ bsem, const float* __restrict__ bepi,
    short* __restrict__ W1t, short* __restrict__ W2t, short* __restrict__ Wpt,
    float* __restrict__ bp)
{
    const int n = blockIdx.x, t = threadIdx.x;
    if (n < 512) {
        W1t[n*256 + t] = f2bf(W1[t*H2_ + n]);
    } else if (n < 768) {
        const int r = n - 512;
        W2t[r*512 + t]       = f2bf(W2[t*H_ + r]);
        W2t[r*512 + t + 256] = f2bf(W2[(t+256)*H_ + r]);
    } else {
        const int r = n - 768;
        Wpt[r*256 + t] = f2bf(r < 128 ? Wsem[t*HALF_ + r] : Wepi[t*HALF_ + (r-128)]);
        if (t == 0) bp[r] = (r < 128) ? bsem[r] : bepi[r-128];
    }
}

// ---------------------------------------------------------------------------
// Fused encode v2: 64 tokens/block, 8 waves. Each wave computes ALL 64 rows
// (4 A-fragments) x 32 N-cols (2 B-fragments) => 4 MFMAs per B-load.
// GEMM1/GEMM2 split into two k-halves so fB is only [64][264] (LDS ~72KB =>
// 2 blocks/CU, 512-block grid = exactly one co-resident round).
// B-fragments prefetched 1 kk-step ahead; all kk loops fully unrolled.
// Fragment convention (consistent A/B => k-permutation cancels):
//   A: row = lo (+16m), k = kk*32 + 8*hi + i   (contiguous bf16x8 from LDS)
//   B: col = lo,        k = same               (contiguous from [N][K] array)
//   C: col = lo, row = hi*4 + r (+16m)         (m89-verified)
// ---------------------------------------------------------------------------
#define EA_LD 264

__global__ __launch_bounds__(512, 4) void k_encode_fused(
    const int* __restrict__ seq, const float* __restrict__ embed,
    const short* __restrict__ W1t, const float* __restrict__ b1,
    const short* __restrict__ W2t, const float* __restrict__ b2,
    const float* __restrict__ ln_g, const float* __restrict__ ln_b,
    const short* __restrict__ Wpt, const float* __restrict__ bp,
    float* __restrict__ kske)
{
    __shared__ __align__(16) short eA[64*EA_LD];   // 33792 B (hA overlays)
    __shared__ __align__(16) short fB[64*EA_LD];   // 33792 B
    __shared__ float2 lnp[8][64];                  // 4096 B
    __shared__ float2 stat[64];                    // 512 B

    const int tid = threadIdx.x;          // 0..511
    const int lo  = tid & 15;
    const int hi  = (tid >> 4) & 3;
    const int wv  = tid >> 6;             // 0..7
    const int n0  = wv * 32;
    const int tokBase = blockIdx.x * 64;
    short* hA = eA;

    // ---- gather embed rows (f32) -> eA (bf16) ----
    {
        const int tk = tid >> 3, part = tid & 7;
        const float4* src = (const float4*)(embed + (size_t)seq[tokBase + tk] * H_);
#pragma unroll
        for (int i = 0; i < 8; ++i) {
            float4 v = src[part + 8*i];
            short4 o; o.x = f2bf(v.x); o.y = f2bf(v.y); o.z = f2bf(v.z); o.w = f2bf(v.w);
            *(short4*)&eA[tk*EA_LD + (part + 8*i)*4] = o;
        }
    }
    __syncthreads();

    f32x4 acc2[4][2];
#pragma unroll
    for (int m = 0; m < 4; ++m) { acc2[m][0] = (f32x4){0,0,0,0}; acc2[m][1] = (f32x4){0,0,0,0}; }

    for (int h = 0; h < 2; ++h) {
        // ---- GEMM1 half: ff1[:, h*256 + n0 .. +32] = e @ W1-half ----
        f32x4 acc1[4][2];
#pragma unroll
        for (int m = 0; m < 4; ++m) { acc1[m][0] = (f32x4){0,0,0,0}; acc1[m][1] = (f32x4){0,0,0,0}; }
        {
            const short* Bb = W1t + ((size_t)(h*256 + n0 + lo))*256;
            bf16x8 bc0 = *(const bf16x8*)(Bb + 8*hi);
            bf16x8 bc1 = *(const bf16x8*)(Bb + 16*256 + 8*hi);
#pragma unroll
            for (int kk = 0; kk < 8; ++kk) {
                const int k0 = kk*32 + 8*hi;
                bf16x8 bn0, bn1;
                if (kk < 7) {
                    bn0 = *(const bf16x8*)(Bb + k0 + 32);
                    bn1 = *(const bf16x8*)(Bb + 16*256 + k0 + 32);
                }
#pragma unroll
                for (int m = 0; m < 4; ++m) {
                    bf16x8 a = *(const bf16x8*)&eA[(lo + 16*m)*EA_LD + k0];
                    acc1[m][0] = __builtin_amdgcn_mfma_f32_16x16x32_bf16(a, bc0, acc1[m][0], 0,0,0);
                    acc1[m][1] = __builtin_amdgcn_mfma_f32_16x16x32_bf16(a, bc1, acc1[m][1], 0,0,0);
                }
                if (kk < 7) { bc0 = bn0; bc1 = bn1; }
            }
        }
        // bias + relu -> fB (bf16)
        {
            const float bb0 = b1[h*256 + n0 + lo];
            const float bb1 = b1[h*256 + n0 + 16 + lo];
#pragma unroll
            for (int m = 0; m < 4; ++m)
#pragma unroll
                for (int r = 0; r < 4; ++r) {
                    const int row = m*16 + hi*4 + r;
                    fB[row*EA_LD + n0 + lo]      = f2bf(fmaxf(acc1[m][0][r] + bb0, 0.f));
                    fB[row*EA_LD + n0 + 16 + lo] = f2bf(fmaxf(acc1[m][1][r] + bb1, 0.f));
                }
        }
        __syncthreads();
        // ---- GEMM2 partial: acc2 += ff1_half @ W2[h*256 .. h*256+256, n0..n0+32] ----
        {
            const short* Bb = W2t + ((size_t)(n0 + lo))*512 + h*256;
            bf16x8 bc0 = *(const bf16x8*)(Bb + 8*hi);
            bf16x8 bc1 = *(const bf16x8*)(Bb + 16*512 + 8*hi);
#pragma unroll
            for (int kk = 0; kk < 8; ++kk) {
                const int k0 = kk*32 + 8*hi;
                bf16x8 bn0, bn1;
                if (kk < 7) {
                    bn0 = *(const bf16x8*)(Bb + k0 + 32);
                    bn1 = *(const bf16x8*)(Bb + 16*512 + k0 + 32);
                }
#pragma unroll
                for (int m = 0; m < 4; ++m) {
                    bf16x8 a = *(const bf16x8*)&fB[(lo + 16*m)*EA_LD + k0];
                    acc2[m][0] = __builtin_amdgcn_mfma_f32_16x16x32_bf16(a, bc0, acc2[m][0], 0,0,0);
                    acc2[m][1] = __builtin_amdgcn_mfma_f32_16x16x32_bf16(a, bc1, acc2[m][1], 0,0,0);
                }
                if (kk < 7) { bc0 = bn0; bc1 = bn1; }
            }
        }
        __syncthreads();   // fB free for next half
    }

    const int col0 = n0 + lo, col1 = n0 + 16 + lo;

    // ---- x = e + ff2 + b2 ; per-row LN partial sums over this wave's 2 cols ----
    {
        const float bb0 = b2[col0], bb1 = b2[col1];
#pragma unroll
        for (int m = 0; m < 4; ++m)
#pragma unroll
            for (int r = 0; r < 4; ++r) {
                const int row = m*16 + hi*4 + r;
                acc2[m][0][r] += bb0 + bf2f(eA[row*EA_LD + col0]);
                acc2[m][1][r] += bb1 + bf2f(eA[row*EA_LD + col1]);
            }
#pragma unroll
        for (int m = 0; m < 4; ++m)
#pragma unroll
            for (int r = 0; r < 4; ++r) {
                float x0 = acc2[m][0][r], x1 = acc2[m][1][r];
                float s  = x0 + x1;
                float s2 = fmaf(x0, x0, x1*x1);
#pragma unroll
                for (int o = 1; o < 16; o <<= 1) { s += __shfl_xor(s, o, 64); s2 += __shfl_xor(s2, o, 64); }
                if (lo == 0) { float2 p; p.x = s; p.y = s2; lnp[wv][m*16 + hi*4 + r] = p; }
            }
    }
    __syncthreads();
    if (tid < 64) {
        float s = 0.f, s2 = 0.f;
#pragma unroll
        for (int w = 0; w < 8; ++w) { float2 p = lnp[w][tid]; s += p.x; s2 += p.y; }
        float mu  = s * (1.f/256.f);
        float var = s2 * (1.f/256.f) - mu*mu;
        float2 st; st.x = mu; st.y = rsqrtf(var + 1e-5f);
        stat[tid] = st;
    }
    __syncthreads();

    // ---- normalize -> hA (overlays eA; all eA reads completed above) ----
    {
        const float g0 = ln_g[col0], g1 = ln_g[col1];
        const float be0 = ln_b[col0], be1 = ln_b[col1];
#pragma unroll
        for (int m = 0; m < 4; ++m)
#pragma unroll
            for (int r = 0; r < 4; ++r) {
                const int row = m*16 + hi*4 + r;
                float2 st = stat[row];
                hA[row*EA_LD + col0] = f2bf((acc2[m][0][r] - st.x) * st.y * g0 + be0);
                hA[row*EA_LD + col1] = f2bf((acc2[m][1][r] - st.x) * st.y * g1 + be1);
            }
    }
    __syncthreads();

    // ---- GEMM3: [ks|ke] = h @ [Wsem|Wepi] + bp -> global f32 ----
    f32x4 acc3[4][2];
#pragma unroll
    for (int m = 0; m < 4; ++m) { acc3[m][0] = (f32x4){0,0,0,0}; acc3[m][1] = (f32x4){0,0,0,0}; }
    {
        const short* Bb = Wpt + ((size_t)(n0 + lo))*256;
        bf16x8 bc0 = *(const bf16x8*)(Bb + 8*hi);
        bf16x8 bc1 = *(const bf16x8*)(Bb + 16*256 + 8*hi);
#pragma unroll
        for (int kk = 0; kk < 8; ++kk) {
            const int k0 = kk*32 + 8*hi;
            bf16x8 bn0, bn1;
            if (kk < 7) {
                bn0 = *(const bf16x8*)(Bb + k0 + 32);
                bn1 = *(const bf16x8*)(Bb + 16*256 + k0 + 32);
            }
#pragma unroll
            for (int m = 0; m < 4; ++m) {
                bf16x8 a = *(const bf16x8*)&hA[(lo + 16*m)*EA_LD + k0];
                acc3[m][0] = __builtin_amdgcn_mfma_f32_16x16x32_bf16(a, bc0, acc3[m][0], 0,0,0);
                acc3[m][1] = __builtin_amdgcn_mfma_f32_16x16x32_bf16(a, bc1, acc3[m][1], 0,0,0);
            }
            if (kk < 7) { bc0 = bn0; bc1 = bn1; }
        }
    }
    {
        const float bp0 = bp[col0], bp1 = bp[col1];
#pragma unroll
        for (int m = 0; m < 4; ++m)
#pragma unroll
            for (int r = 0; r < 4; ++r) {
                const int row = m*16 + hi*4 + r;
                kske[(size_t)(tokBase + row)*256 + col0] = acc3[m][0][r] + bp0;
                kske[(size_t)(tokBase + row)*256 + col1] = acc3[m][1][r] + bp1;
            }
    }
}

// ---------------------------------------------------------------------------
// k_gram: per (batch, chain, chunk of 16) 16x16 Gram via split-bf16 MFMA;
// stores pre-negated column-scaled G' = -gamma_j*G_ij and -gamma. (unchanged)
// ---------------------------------------------------------------------------
__global__ __launch_bounds__(64) void k_gram(
    const float* __restrict__ kske, float* __restrict__ Gp, float* __restrict__ gv)
{
    const int c = blockIdx.x, chain = blockIdx.y, b = blockIdx.z;
    const int l = threadIdx.x, lo = l & 15, hi = l >> 4;
    const size_t rowbase = ((size_t)(b*L_ + c*16 + lo))*256 + chain*HALF_ + 8*hi;

    bf16x8 ah[4], al[4];
#pragma unroll
    for (int m = 0; m < 4; ++m) {
        float4 v0 = *(const float4*)(kske + rowbase + m*32);
        float4 v1 = *(const float4*)(kske + rowbase + m*32 + 4);
        float f[8] = {v0.x,v0.y,v0.z,v0.w,v1.x,v1.y,v1.z,v1.w};
#pragma unroll
        for (int i = 0; i < 8; ++i) {
            short h = f2bf(f[i]);
            ah[m][i] = h;
            al[m][i] = f2bf(f[i] - bf2f(h));
        }
    }
    f32x4 g = {0.f,0.f,0.f,0.f};
#pragma unroll
    for (int m = 0; m < 4; ++m) {
        g = __builtin_amdgcn_mfma_f32_16x16x32_bf16(ah[m], ah[m], g, 0,0,0);
        g = __builtin_amdgcn_mfma_f32_16x16x32_bf16(ah[m], al[m], g, 0,0,0);
        g = __builtin_amdgcn_mfma_f32_16x16x32_bf16(al[m], ah[m], g, 0,0,0);
    }
    __shared__ float diag[16];
#pragma unroll
    for (int r = 0; r < 4; ++r)
        if (4*hi + r == lo) diag[lo] = g[r];
    __syncthreads();
    const int tcol = c*16 + lo;
    float beta = 1.f / (diag[lo] + 1e-6f);
    float gam  = chain ? ((float)(tcol+1) * (1.f/512.f)) * beta : beta;
    if (tcol == 511) gam = 0.f;
    const size_t gbase = ((size_t)((b*2 + chain)*32 + c))*256;
#pragma unroll
    for (int r = 0; r < 4; ++r)
        Gp[gbase + (size_t)(4*hi+r)*16 + lo] = -gam * g[r];
    if (l < 16) gv[((b*2 + chain)*32 + c)*16 + lo] = -gam;
}

// ---------------------------------------------------------------------------
// k_scan: chunked WY backward scan (unchanged — verified round 2).
// ---------------------------------------------------------------------------
#define SCAN_BODY(CC, GA, KXA, KYA, NGA, GB, KXB, KYB, NGB) do {              \
    const int c_ = (CC);                                                      \
    wls[2*l] = w.x; wls[2*l+1] = w.y;                                         \
    float p0=0.f, p1=0.f, p2=0.f, p3=0.f;                                     \
    _Pragma("unroll")                                                         \
    for (int i = 0; i < 8; ++i) {                                             \
        float4 wv = *(const float4*)&wls[q*32 + 4*i];                         \
        p0 = fmaf(kq[i].x, wv.x, p0); p1 = fmaf(kq[i].y, wv.y, p1);           \
        p2 = fmaf(kq[i].z, wv.z, p2); p3 = fmaf(kq[i].w, wv.w, p3);           \
    }                                                                         \
    float bb = (p0 + p1) + (p2 + p3);                                         \
    bb += __shfl_xor(bb, 16, 64);                                             \
    bb += __shfl_xor(bb, 32, 64);                                             \
    if (c_ > 0) {                                                             \
        const float* krow = kb + ((size_t)((c_-1)*16 + lo))*256 + q*32;       \
        _Pragma("unroll")                                                     \
        for (int i = 0; i < 8; ++i) kq[i] = *(const float4*)(krow + 4*i);     \
        const float* gr = gpb + (size_t)(c_-1)*256 + lo*16;                   \
        _Pragma("unroll")                                                     \
        for (int i = 0; i < 4; ++i) {                                         \
            float4 gt = *(const float4*)(gr + 4*i);                           \
            GB[4*i]=gt.x; GB[4*i+1]=gt.y; GB[4*i+2]=gt.z; GB[4*i+3]=gt.w;     \
        }                                                                     \
        NGB = gvb[(c_-1)*16 + lo];                                            \
        const float* kdr = kb + ((size_t)((c_-1)*16))*256 + 2*l;              \
        _Pragma("unroll")                                                     \
        for (int j = 0; j < 16; ++j) {                                        \
            float2 kt = *(const float2*)(kdr + (size_t)j*256);                \
            KXB[j] = kt.x; KYB[j] = kt.y;                                     \
        }                                                                     \
    }                                                                         \
    const int tl_ = c_*16 + lo;                                               \
    const float cl_ = chain ? ((tl_ < 511) ? (float)(tl_+1)*(1.f/512.f) : 0.f)\
                            : ((tl_ < 511) ? 1.f : 0.f);                      \
    _Pragma("unroll")                                                         \
    for (int j = 15; j >= 0; --j) {                                           \
        float dj = __int_as_float(__builtin_amdgcn_readlane(__float_as_int(bb), j)); \
        bb = fmaf(dj, GA[j], bb);                                             \
        float tg = NGA * dj;                                                  \
        float tc = cl_ * dj;                                                  \
        float gd = __int_as_float(__builtin_amdgcn_readlane(__float_as_int(tg), j)); \
        float cd = __int_as_float(__builtin_amdgcn_readlane(__float_as_int(tc), j)); \
        w.x = fmaf(gd, KXA[j], w.x);  w.y = fmaf(gd, KYA[j], w.y);            \
        ax  = fmaf(cd, KXA[j], ax);   ay  = fmaf(cd, KYA[j], ay);             \
    }                                                                         \
} while (0)

__global__ __launch_bounds__(64) void k_scan(
    const float* __restrict__ kske, const float* __restrict__ Gp,
    const float* __restrict__ gv, float* __restrict__ cvec)
{
    __shared__ float wls[128];
    const int b = blockIdx.x, chain = blockIdx.y;
    const int l = threadIdx.x, lo = l & 15, q = l >> 4;
    const float* kb  = kske + ((size_t)b*L_)*256 + chain*HALF_;
    const float* gpb = Gp + ((size_t)((b*2+chain)*32))*256;
    const float* gvb = gv + ((b*2+chain)*32)*16;

    float2 w = *(const float2*)(kb + (size_t)511*256 + 2*l);
    float ax = 0.f, ay = 0.f;

    float ga[16], kxa[16], kya[16], nga;
    float gb_[16], kxb[16], kyb[16], ngb;
    float4 kq[8];

    {
        const float* krow = kb + ((size_t)(31*16 + lo))*256 + q*32;
#pragma unroll
        for (int i = 0; i < 8; ++i) kq[i] = *(const float4*)(krow + 4*i);
        const float* gr = gpb + (size_t)31*256 + lo*16;
#pragma unroll
        for (int i = 0; i < 4; ++i) {
            float4 gt = *(const float4*)(gr + 4*i);
            ga[4*i]=gt.x; ga[4*i+1]=gt.y; ga[4*i+2]=gt.z; ga[4*i+3]=gt.w;
        }
        nga = gvb[31*16 + lo];
        const float* kdr = kb + ((size_t)(31*16))*256 + 2*l;
#pragma unroll
        for (int j = 0; j < 16; ++j) {
            float2 kt = *(const float2*)(kdr + (size_t)j*256);
            kxa[j] = kt.x; kya[j] = kt.y;
        }
    }

    for (int it = 0; it < 16; ++it) {
        SCAN_BODY(31 - 2*it, ga,  kxa, kya, nga, gb_, kxb, kyb, ngb);
        SCAN_BODY(30 - 2*it, gb_, kxb, kyb, ngb, ga,  kxa, kya, nga);
    }

    float2 outv; outv.x = ax; outv.y = ay;
    *(float2*)(cvec + b*256 + chain*HALF_ + 2*l) = outv;
}

// ---------------------------------------------------------------------------
// K4: out[64][32000] = [cs|ce] @ Wout + bout. float2-vectorized Wout loads,
// 128 cols/block (250 blocks), unroll-4 i-loop for load pipelining.
// ---------------------------------------------------------------------------
__global__ __launch_bounds__(256) void k_out(
    const float* __restrict__ cvec, const float* __restrict__ Wout,
    const float* __restrict__ bout, float* __restrict__ out)
{
    __shared__ float c_s[64][256];
    const int t = threadIdx.x;
    {
        float* flat = &c_s[0][0];
#pragma unroll
        for (int r = 0; r < 64; ++r) flat[t + r*256] = cvec[t + r*256];
    }
    __syncthreads();

    const int col = blockIdx.x * 128 + (t & 63) * 2;
    const int bg  = (t >> 6) * 16;
    float accx[16], accy[16];
#pragma unroll
    for (int i = 0; i < 16; ++i) { accx[i] = 0.f; accy[i] = 0.f; }

#pragma unroll 4
    for (int i = 0; i < 256; ++i) {
        float2 wv = *(const float2*)&Wout[(size_t)i*V_ + col];
#pragma unroll
        for (int bb = 0; bb < 16; ++bb) {
            float cv = c_s[bg + bb][i];
            accx[bb] = fmaf(cv, wv.x, accx[bb]);
            accy[bb] = fmaf(cv, wv.y, accy[bb]);
        }
    }
    const float bo0 = bout[col], bo1 = bout[col+1];
#pragma unroll
    for (int bb = 0; bb < 16; ++bb) {
        float2 o; o.x = accx[bb] + bo0; o.y = accy[bb] + bo1;
        *(float2*)&out[(size_t)(bg + bb)*V_ + col] = o;
    }
}

// ---------------------------------------------------------------------------
extern "C" void kernel_launch(void* const* d_in, const int* in_sizes, int n_in,
                              void* d_out, int out_size, void* d_ws, size_t ws_size,
                              hipStream_t stream)
{
    (void)in_sizes; (void)n_in; (void)out_size; (void)ws_size;
    const int*   seq   = (const int*)  d_in[0];
    const float* embed = (const float*)d_in[1];
    const float* W1    = (const float*)d_in[2];
    const float* b1    = (const float*)d_in[3];
    const float* W2    = (const float*)d_in[4];
    const float* b2    = (const float*)d_in[5];
    const float* ln_g  = (const float*)d_in[6];
    const float* ln_b  = (const float*)d_in[7];
    const float* Wsem  = (const float*)d_in[8];
    const float* bsem  = (const float*)d_in[9];
    const float* Wepi  = (const float*)d_in[10];
    const float* bepi  = (const float*)d_in[11];
    const float* Wout  = (const float*)d_in[12];
    const float* bout  = (const float*)d_in[13];
    float* out = (float*)d_out;

    char* wp = (char*)d_ws;
    short* W1t = (short*)wp;  wp += (size_t)512*256*2;
    short* W2t = (short*)wp;  wp += (size_t)256*512*2;
    short* Wpt = (short*)wp;  wp += (size_t)256*256*2;
    float* bp  = (float*)wp;  wp += 256*4;
    float* kske= (float*)wp;  wp += (size_t)NTOK_*256*4;
    float* Gp  = (float*)wp;  wp += (size_t)128*32*256*4;
    float* gv  = (float*)wp;  wp += (size_t)128*32*16*4;
    float* cvec= (float*)wp;

    k_prep<<<1024, 256, 0, stream>>>(W1, W2, Wsem, Wepi, bsem, bepi, W1t, W2t, Wpt, bp);
    k_encode_fused<<<NTOK_/64, 512, 0, stream>>>(seq, embed, W1t, b1, W2t, b2,
                                                 ln_g, ln_b, Wpt, bp, kske);
    k_gram<<<dim3(32, 2, B_), 64, 0, stream>>>(kske, Gp, gv);
    k_scan<<<dim3(B_, 2), 64, 0, stream>>>(kske, Gp, gv, cvec);
    k_out<<<V_/128, 256, 0, stream>>>(cvec, Wout, bout, out);
}

// Round 5
// 132.336 us; speedup vs baseline: 4.4810x; 1.0035x over previous
//
#include <hip/hip_runtime.h>
#include <hip/hip_bf16.h>
#include <stdint.h>

#define B_   64
#define L_   512
#define H_   256
#define H2_  512
#define HALF_ 128
#define V_   32000
#define NTOK_ (B_*L_)

typedef __attribute__((ext_vector_type(8))) short bf16x8;
typedef __attribute__((ext_vector_type(4))) float f32x4;

__device__ __forceinline__ float bf2f(short h){
    union { unsigned u; float f; } v; v.u = ((unsigned)(unsigned short)h) << 16; return v.f;
}
__device__ __forceinline__ short f2bf(float f){
    union { float f; unsigned u; } v; v.f = f;
    unsigned r = v.u + 0x7fffu + ((v.u >> 16) & 1u);   // RNE
    return (short)(r >> 16);
}

// ---------------------------------------------------------------------------
// Prep: bf16-transpose weights so MFMA B-fragments are contiguous 16B loads.
// ---------------------------------------------------------------------------
__global__ __launch_bounds__(256) void k_prep(
    const float* __restrict__ W1, const float* __restrict__ W2,
    const float* __restrict__ Wsem, const float* __restrict__ Wepi,
    const float* __restrict__ bsem, const float* __restrict__ bepi,
    short* __restrict__ W1t, short* __restrict__ W2t, short* __restrict__ Wpt,
    float* __restrict__ bp)
{
    const int n = blockIdx.x, t = threadIdx.x;
    if (n < 512) {
        W1t[n*256 + t] = f2bf(W1[t*H2_ + n]);
    } else if (n < 768) {
        const int r = n - 512;
        W2t[r*512 + t]       = f2bf(W2[t*H_ + r]);
        W2t[r*512 + t + 256] = f2bf(W2[(t+256)*H_ + r]);
    } else {
        const int r = n - 768;
        Wpt[r*256 + t] = f2bf(r < 128 ? Wsem[t*HALF_ + r] : Wepi[t*HALF_ + (r-128)]);
        if (t == 0) bp[r] = (r < 128) ? bsem[r] : bepi[r-128];
    }
}

// ---------------------------------------------------------------------------
// Fused encode v2: 64 tokens/block, 8 waves. Each wave computes ALL 64 rows
// (4 A-fragments) x 32 N-cols (2 B-fragments) => 4 MFMAs per B-load.
// GEMM1/GEMM2 split into two k-halves so fB is only [64][264] (LDS ~72KB =>
// 2 blocks/CU, 512-block grid = exactly one co-resident round).
// B-fragments prefetched 1 kk-step ahead; all kk loops fully unrolled.
// Fragment convention (consistent A/B => k-permutation cancels):
//   A: row = lo (+16m), k = kk*32 + 8*hi + i   (contiguous bf16x8 from LDS)
//   B: col = lo,        k = same               (contiguous from [N][K] array)
//   C: col = lo, row = hi*4 + r (+16m)         (m89-verified)
// ---------------------------------------------------------------------------
#define EA_LD 264

__global__ __launch_bounds__(512, 4) void k_encode_fused(
    const int* __restrict__ seq, const float* __restrict__ embed,
    const short* __restrict__ W1t, const float* __restrict__ b1,
    const short* __restrict__ W2t, const float* __restrict__ b2,
    const float* __restrict__ ln_g, const float* __restrict__ ln_b,
    const short* __restrict__ Wpt, const float* __restrict__ bp,
    float* __restrict__ kske)
{
    __shared__ __align__(16) short eA[64*EA_LD];   // 33792 B (hA overlays)
    __shared__ __align__(16) short fB[64*EA_LD];   // 33792 B
    __shared__ float2 lnp[8][64];                  // 4096 B
    __shared__ float2 stat[64];                    // 512 B

    const int tid = threadIdx.x;          // 0..511
    const int lo  = tid & 15;
    const int hi  = (tid >> 4) & 3;
    const int wv  = tid >> 6;             // 0..7
    const int n0  = wv * 32;
    const int tokBase = blockIdx.x * 64;
    short* hA = eA;

    // ---- gather embed rows (f32) -> eA (bf16) ----
    {
        const int tk = tid >> 3, part = tid & 7;
        const float4* src = (const float4*)(embed + (size_t)seq[tokBase + tk] * H_);
#pragma unroll
        for (int i = 0; i < 8; ++i) {
            float4 v = src[part + 8*i];
            short4 o; o.x = f2bf(v.x); o.y = f2bf(v.y); o.z = f2bf(v.z); o.w = f2bf(v.w);
            *(short4*)&eA[tk*EA_LD + (part + 8*i)*4] = o;
        }
    }
    __syncthreads();

    f32x4 acc2[4][2];
#pragma unroll
    for (int m = 0; m < 4; ++m) { acc2[m][0] = (f32x4){0,0,0,0}; acc2[m][1] = (f32x4){0,0,0,0}; }

    for (int h = 0; h < 2; ++h) {
        // ---- GEMM1 half: ff1[:, h*256 + n0 .. +32] = e @ W1-half ----
        f32x4 acc1[4][2];
#pragma unroll
        for (int m = 0; m < 4; ++m) { acc1[m][0] = (f32x4){0,0,0,0}; acc1[m][1] = (f32x4){0,0,0,0}; }
        {
            const short* Bb = W1t + ((size_t)(h*256 + n0 + lo))*256;
            bf16x8 bc0 = *(const bf16x8*)(Bb + 8*hi);
            bf16x8 bc1 = *(const bf16x8*)(Bb + 16*256 + 8*hi);
#pragma unroll
            for (int kk = 0; kk < 8; ++kk) {
                const int k0 = kk*32 + 8*hi;
                bf16x8 bn0, bn1;
                if (kk < 7) {
                    bn0 = *(const bf16x8*)(Bb + k0 + 32);
                    bn1 = *(const bf16x8*)(Bb + 16*256 + k0 + 32);
                }
#pragma unroll
                for (int m = 0; m < 4; ++m) {
                    bf16x8 a = *(const bf16x8*)&eA[(lo + 16*m)*EA_LD + k0];
                    acc1[m][0] = __builtin_amdgcn_mfma_f32_16x16x32_bf16(a, bc0, acc1[m][0], 0,0,0);
                    acc1[m][1] = __builtin_amdgcn_mfma_f32_16x16x32_bf16(a, bc1, acc1[m][1], 0,0,0);
                }
                if (kk < 7) { bc0 = bn0; bc1 = bn1; }
            }
        }
        // bias + relu -> fB (bf16)
        {
            const float bb0 = b1[h*256 + n0 + lo];
            const float bb1 = b1[h*256 + n0 + 16 + lo];
#pragma unroll
            for (int m = 0; m < 4; ++m)
#pragma unroll
                for (int r = 0; r < 4; ++r) {
                    const int row = m*16 + hi*4 + r;
                    fB[row*EA_LD + n0 + lo]      = f2bf(fmaxf(acc1[m][0][r] + bb0, 0.f));
                    fB[row*EA_LD + n0 + 16 + lo] = f2bf(fmaxf(acc1[m][1][r] + bb1, 0.f));
                }
        }
        __syncthreads();
        // ---- GEMM2 partial: acc2 += ff1_half @ W2[h*256 .. h*256+256, n0..n0+32] ----
        {
            const short* Bb = W2t + ((size_t)(n0 + lo))*512 + h*256;
            bf16x8 bc0 = *(const bf16x8*)(Bb + 8*hi);
            bf16x8 bc1 = *(const bf16x8*)(Bb + 16*512 + 8*hi);
#pragma unroll
            for (int kk = 0; kk < 8; ++kk) {
                const int k0 = kk*32 + 8*hi;
                bf16x8 bn0, bn1;
                if (kk < 7) {
                    bn0 = *(const bf16x8*)(Bb + k0 + 32);
                    bn1 = *(const bf16x8*)(Bb + 16*512 + k0 + 32);
                }
#pragma unroll
                for (int m = 0; m < 4; ++m) {
                    bf16x8 a = *(const bf16x8*)&fB[(lo + 16*m)*EA_LD + k0];
                    acc2[m][0] = __builtin_amdgcn_mfma_f32_16x16x32_bf16(a, bc0, acc2[m][0], 0,0,0);
                    acc2[m][1] = __builtin_amdgcn_mfma_f32_16x16x32_bf16(a, bc1, acc2[m][1], 0,0,0);
                }
                if (kk < 7) { bc0 = bn0; bc1 = bn1; }
            }
        }
        __syncthreads();   // fB free for next half
    }

    const int col0 = n0 + lo, col1 = n0 + 16 + lo;

    // ---- x = e + ff2 + b2 ; per-row LN partial sums over this wave's 2 cols ----
    {
        const float bb0 = b2[col0], bb1 = b2[col1];
#pragma unroll
        for (int m = 0; m < 4; ++m)
#pragma unroll
            for (int r = 0; r < 4; ++r) {
                const int row = m*16 + hi*4 + r;
                acc2[m][0][r] += bb0 + bf2f(eA[row*EA_LD + col0]);
                acc2[m][1][r] += bb1 + bf2f(eA[row*EA_LD + col1]);
            }
#pragma unroll
        for (int m = 0; m < 4; ++m)
#pragma unroll
            for (int r = 0; r < 4; ++r) {
                float x0 = acc2[m][0][r], x1 = acc2[m][1][r];
                float s  = x0 + x1;
                float s2 = fmaf(x0, x0, x1*x1);
#pragma unroll
                for (int o = 1; o < 16; o <<= 1) { s += __shfl_xor(s, o, 64); s2 += __shfl_xor(s2, o, 64); }
                if (lo == 0) { float2 p; p.x = s; p.y = s2; lnp[wv][m*16 + hi*4 + r] = p; }
            }
    }
    __syncthreads();
    if (tid < 64) {
        float s = 0.f, s2 = 0.f;
#pragma unroll
        for (int w = 0; w < 8; ++w) { float2 p = lnp[w][tid]; s += p.x; s2 += p.y; }
        float mu  = s * (1.f/256.f);
        float var = s2 * (1.f/256.f) - mu*mu;
        float2 st; st.x = mu; st.y = rsqrtf(var + 1e-5f);
        stat[tid] = st;
    }
    __syncthreads();

    // ---- normalize -> hA (overlays eA; all eA reads completed above) ----
    {
        const float g0 = ln_g[col0], g1 = ln_g[col1];
        const float be0 = ln_b[col0], be1 = ln_b[col1];
#pragma unroll
        for (int m = 0; m < 4; ++m)
#pragma unroll
            for (int r = 0; r < 4; ++r) {
                const int row = m*16 + hi*4 + r;
                float2 st = stat[row];
                hA[row*EA_LD + col0] = f2bf((acc2[m][0][r] - st.x) * st.y * g0 + be0);
                hA[row*EA_LD + col1] = f2bf((acc2[m][1][r] - st.x) * st.y * g1 + be1);
            }
    }
    __syncthreads();

    // ---- GEMM3: [ks|ke] = h @ [Wsem|Wepi] + bp -> global f32 ----
    f32x4 acc3[4][2];
#pragma unroll
    for (int m = 0; m < 4; ++m) { acc3[m][0] = (f32x4){0,0,0,0}; acc3[m][1] = (f32x4){0,0,0,0}; }
    {
        const short* Bb = Wpt + ((size_t)(n0 + lo))*256;
        bf16x8 bc0 = *(const bf16x8*)(Bb + 8*hi);
        bf16x8 bc1 = *(const bf16x8*)(Bb + 16*256 + 8*hi);
#pragma unroll
        for (int kk = 0; kk < 8; ++kk) {
            const int k0 = kk*32 + 8*hi;
            bf16x8 bn0, bn1;
            if (kk < 7) {
                bn0 = *(const bf16x8*)(Bb + k0 + 32);
                bn1 = *(const bf16x8*)(Bb + 16*256 + k0 + 32);
            }
#pragma unroll
            for (int m = 0; m < 4; ++m) {
                bf16x8 a = *(const bf16x8*)&hA[(lo + 16*m)*EA_LD + k0];
                acc3[m][0] = __builtin_amdgcn_mfma_f32_16x16x32_bf16(a, bc0, acc3[m][0], 0,0,0);
                acc3[m][1] = __builtin_amdgcn_mfma_f32_16x16x32_bf16(a, bc1, acc3[m][1], 0,0,0);
            }
            if (kk < 7) { bc0 = bn0; bc1 = bn1; }
        }
    }
    {
        const float bp0 = bp[col0], bp1 = bp[col1];
#pragma unroll
        for (int m = 0; m < 4; ++m)
#pragma unroll
            for (int r = 0; r < 4; ++r) {
                const int row = m*16 + hi*4 + r;
                kske[(size_t)(tokBase + row)*256 + col0] = acc3[m][0][r] + bp0;
                kske[(size_t)(tokBase + row)*256 + col1] = acc3[m][1][r] + bp1;
            }
    }
}

// ---------------------------------------------------------------------------
// k_gram: per (batch, chain, chunk of 16) 16x16 Gram via split-bf16 MFMA;
// stores pre-negated column-scaled G' = -gamma_j*G_ij and -gamma. (unchanged)
// ---------------------------------------------------------------------------
__global__ __launch_bounds__(64) void k_gram(
    const float* __restrict__ kske, float* __restrict__ Gp, float* __restrict__ gv)
{
    const int c = blockIdx.x, chain = blockIdx.y, b = blockIdx.z;
    const int l = threadIdx.x, lo = l & 15, hi = l >> 4;
    const size_t rowbase = ((size_t)(b*L_ + c*16 + lo))*256 + chain*HALF_ + 8*hi;

    bf16x8 ah[4], al[4];
#pragma unroll
    for (int m = 0; m < 4; ++m) {
        float4 v0 = *(const float4*)(kske + rowbase + m*32);
        float4 v1 = *(const float4*)(kske + rowbase + m*32 + 4);
        float f[8] = {v0.x,v0.y,v0.z,v0.w,v1.x,v1.y,v1.z,v1.w};
#pragma unroll
        for (int i = 0; i < 8; ++i) {
            short h = f2bf(f[i]);
            ah[m][i] = h;
            al[m][i] = f2bf(f[i] - bf2f(h));
        }
    }
    f32x4 g = {0.f,0.f,0.f,0.f};
#pragma unroll
    for (int m = 0; m < 4; ++m) {
        g = __builtin_amdgcn_mfma_f32_16x16x32_bf16(ah[m], ah[m], g, 0,0,0);
        g = __builtin_amdgcn_mfma_f32_16x16x32_bf16(ah[m], al[m], g, 0,0,0);
        g = __builtin_amdgcn_mfma_f32_16x16x32_bf16(al[m], ah[m], g, 0,0,0);
    }
    __shared__ float diag[16];
#pragma unroll
    for (int r = 0; r < 4; ++r)
        if (4*hi + r == lo) diag[lo] = g[r];
    __syncthreads();
    const int tcol = c*16 + lo;
    float beta = 1.f / (diag[lo] + 1e-6f);
    float gam  = chain ? ((float)(tcol+1) * (1.f/512.f)) * beta : beta;
    if (tcol == 511) gam = 0.f;
    const size_t gbase = ((size_t)((b*2 + chain)*32 + c))*256;
#pragma unroll
    for (int r = 0; r < 4; ++r)
        Gp[gbase + (size_t)(4*hi+r)*16 + lo] = -gam * g[r];
    if (l < 16) gv[((b*2 + chain)*32 + c)*16 + lo] = -gam;
}

// ---------------------------------------------------------------------------
// k_scan: chunked WY backward scan (unchanged — verified round 2).
// ---------------------------------------------------------------------------
#define SCAN_BODY(CC, GA, KXA, KYA, NGA, GB, KXB, KYB, NGB) do {              \
    const int c_ = (CC);                                                      \
    wls[2*l] = w.x; wls[2*l+1] = w.y;                                         \
    float p0=0.f, p1=0.f, p2=0.f, p3=0.f;                                     \
    _Pragma("unroll")                                                         \
    for (int i = 0; i < 8; ++i) {                                             \
        float4 wv = *(const float4*)&wls[q*32 + 4*i];                         \
        p0 = fmaf(kq[i].x, wv.x, p0); p1 = fmaf(kq[i].y, wv.y, p1);           \
        p2 = fmaf(kq[i].z, wv.z, p2); p3 = fmaf(kq[i].w, wv.w, p3);           \
    }                                                                         \
    float bb = (p0 + p1) + (p2 + p3);                                         \
    bb += __shfl_xor(bb, 16, 64);                                             \
    bb += __shfl_xor(bb, 32, 64);                                             \
    if (c_ > 0) {                                                             \
        const float* krow = kb + ((size_t)((c_-1)*16 + lo))*256 + q*32;       \
        _Pragma("unroll")                                                     \
        for (int i = 0; i < 8; ++i) kq[i] = *(const float4*)(krow + 4*i);     \
        const float* gr = gpb + (size_t)(c_-1)*256 + lo*16;                   \
        _Pragma("unroll")                                                     \
        for (int i = 0; i < 4; ++i) {                                         \
            float4 gt = *(const float4*)(gr + 4*i);                           \
            GB[4*i]=gt.x; GB[4*i+1]=gt.y; GB[4*i+2]=gt.z; GB[4*i+3]=gt.w;     \
        }                                                                     \
        NGB = gvb[(c_-1)*16 + lo];                                            \
        const float* kdr = kb + ((size_t)((c_-1)*16))*256 + 2*l;              \
        _Pragma("unroll")                                                     \
        for (int j = 0; j < 16; ++j) {                                        \
            float2 kt = *(const float2*)(kdr + (size_t)j*256);                \
            KXB[j] = kt.x; KYB[j] = kt.y;                                     \
        }                                                                     \
    }                                                                         \
    const int tl_ = c_*16 + lo;                                               \
    const float cl_ = chain ? ((tl_ < 511) ? (float)(tl_+1)*(1.f/512.f) : 0.f)\
                            : ((tl_ < 511) ? 1.f : 0.f);                      \
    _Pragma("unroll")                                                         \
    for (int j = 15; j >= 0; --j) {                                           \
        float dj = __int_as_float(__builtin_amdgcn_readlane(__float_as_int(bb), j)); \
        bb = fmaf(dj, GA[j], bb);                                             \
        float tg = NGA * dj;                                                  \
        float tc = cl_ * dj;                                                  \
        float gd = __int_as_float(__builtin_amdgcn_readlane(__float_as_int(tg), j)); \
        float cd = __int_as_float(__builtin_amdgcn_readlane(__float_as_int(tc), j)); \
        w.x = fmaf(gd, KXA[j], w.x);  w.y = fmaf(gd, KYA[j], w.y);            \
        ax  = fmaf(cd, KXA[j], ax);   ay  = fmaf(cd, KYA[j], ay);             \
    }                                                                         \
} while (0)

__global__ __launch_bounds__(64) void k_scan(
    const float* __restrict__ kske, const float* __restrict__ Gp,
    const float* __restrict__ gv, float* __restrict__ cvec)
{
    __shared__ float wls[128];
    const int b = blockIdx.x, chain = blockIdx.y;
    const int l = threadIdx.x, lo = l & 15, q = l >> 4;
    const float* kb  = kske + ((size_t)b*L_)*256 + chain*HALF_;
    const float* gpb = Gp + ((size_t)((b*2+chain)*32))*256;
    const float* gvb = gv + ((b*2+chain)*32)*16;

    float2 w = *(const float2*)(kb + (size_t)511*256 + 2*l);
    float ax = 0.f, ay = 0.f;

    float ga[16], kxa[16], kya[16], nga;
    float gb_[16], kxb[16], kyb[16], ngb;
    float4 kq[8];

    {
        const float* krow = kb + ((size_t)(31*16 + lo))*256 + q*32;
#pragma unroll
        for (int i = 0; i < 8; ++i) kq[i] = *(const float4*)(krow + 4*i);
        const float* gr = gpb + (size_t)31*256 + lo*16;
#pragma unroll
        for (int i = 0; i < 4; ++i) {
            float4 gt = *(const float4*)(gr + 4*i);
            ga[4*i]=gt.x; ga[4*i+1]=gt.y; ga[4*i+2]=gt.z; ga[4*i+3]=gt.w;
        }
        nga = gvb[31*16 + lo];
        const float* kdr = kb + ((size_t)(31*16))*256 + 2*l;
#pragma unroll
        for (int j = 0; j < 16; ++j) {
            float2 kt = *(const float2*)(kdr + (size_t)j*256);
            kxa[j] = kt.x; kya[j] = kt.y;
        }
    }

    for (int it = 0; it < 16; ++it) {
        SCAN_BODY(31 - 2*it, ga,  kxa, kya, nga, gb_, kxb, kyb, ngb);
        SCAN_BODY(30 - 2*it, gb_, kxb, kyb, ngb, ga,  kxa, kya, nga);
    }

    float2 outv; outv.x = ax; outv.y = ay;
    *(float2*)(cvec + b*256 + chain*HALF_ + 2*l) = outv;
}

// ---------------------------------------------------------------------------
// K4: out[64][32000] = [cs|ce] @ Wout + bout. float2-vectorized Wout loads,
// 128 cols/block (250 blocks), unroll-4 i-loop for load pipelining.
// ---------------------------------------------------------------------------
__global__ __launch_bounds__(256) void k_out(
    const float* __restrict__ cvec, const float* __restrict__ Wout,
    const float* __restrict__ bout, float* __restrict__ out)
{
    __shared__ float c_s[64][256];
    const int t = threadIdx.x;
    {
        float* flat = &c_s[0][0];
#pragma unroll
        for (int r = 0; r < 64; ++r) flat[t + r*256] = cvec[t + r*256];
    }
    __syncthreads();

    const int col = blockIdx.x * 128 + (t & 63) * 2;
    const int bg  = (t >> 6) * 16;
    float accx[16], accy[16];
#pragma unroll
    for (int i = 0; i < 16; ++i) { accx[i] = 0.f; accy[i] = 0.f; }

#pragma unroll 4
    for (int i = 0; i < 256; ++i) {
        float2 wv = *(const float2*)&Wout[(size_t)i*V_ + col];
#pragma unroll
        for (int bb = 0; bb < 16; ++bb) {
            float cv = c_s[bg + bb][i];
            accx[bb] = fmaf(cv, wv.x, accx[bb]);
            accy[bb] = fmaf(cv, wv.y, accy[bb]);
        }
    }
    const float bo0 = bout[col], bo1 = bout[col+1];
#pragma unroll
    for (int bb = 0; bb < 16; ++bb) {
        float2 o; o.x = accx[bb] + bo0; o.y = accy[bb] + bo1;
        *(float2*)&out[(size_t)(bg + bb)*V_ + col] = o;
    }
}

// ---------------------------------------------------------------------------
extern "C" void kernel_launch(void* const* d_in, const int* in_sizes, int n_in,
                              void* d_out, int out_size, void* d_ws, size_t ws_size,
                              hipStream_t stream)
{
    (void)in_sizes; (void)n_in; (void)out_size; (void)ws_size;
    const int*   seq   = (const int*)  d_in[0];
    const float* embed = (const float*)d_in[1];
    const float* W1    = (const float*)d_in[2];
    const float* b1    = (const float*)d_in[3];
    const float* W2    = (const float*)d_in[4];
    const float* b2    = (const float*)d_in[5];
    const float* ln_g  = (const float*)d_in[6];
    const float* ln_b  = (const float*)d_in[7];
    const float* Wsem  = (const float*)d_in[8];
    const float* bsem  = (const float*)d_in[9];
    const float* Wepi  = (const float*)d_in[10];
    const float* bepi  = (const float*)d_in[11];
    const float* Wout  = (const float*)d_in[12];
    const float* bout  = (const float*)d_in[13];
    float* out = (float*)d_out;

    char* wp = (char*)d_ws;
    short* W1t = (short*)wp;  wp += (size_t)512*256*2;
    short* W2t = (short*)wp;  wp += (size_t)256*512*2;
    short* Wpt = (short*)wp;  wp += (size_t)256*256*2;
    float* bp  = (float*)wp;  wp += 256*4;
    float* kske= (float*)wp;  wp += (size_t)NTOK_*256*4;
    float* Gp  = (float*)wp;  wp += (size_t)128*32*256*4;
    float* gv  = (float*)wp;  wp += (size_t)128*32*16*4;
    float* cvec= (float*)wp;

    k_prep<<<1024, 256, 0, stream>>>(W1, W2, Wsem, Wepi, bsem, bepi, W1t, W2t, Wpt, bp);
    k_encode_fused<<<NTOK_/64, 512, 0, stream>>>(seq, embed, W1t, b1, W2t, b2,
                                                 ln_g, ln_b, Wpt, bp, kske);
    k_gram<<<dim3(32, 2, B_), 64, 0, stream>>>(kske, Gp, gv);
    k_scan<<<dim3(B_, 2), 64, 0, stream>>>(kske, Gp, gv, cvec);
    k_out<<<V_/128, 256, 0, stream>>>(cvec, Wout, bout, out);
}